// Round 1
// baseline (3853.525 us; speedup 1.0000x reference)
//
#include <hip/hip_runtime.h>

#define DEVFN __device__ __forceinline__

static inline int ceil_div(int a, int b) { return (a + b - 1) / b; }

// ---------------------------------------------------------------------------
// Farthest point sampling. One block per batch. Exact fp32 (no FMA) distance
// arithmetic to match numpy bit-for-bit; first-occurrence argmax tie-break.
// ---------------------------------------------------------------------------
template<int N, int M>
__global__ __launch_bounds__(256) void fps_kernel(const float* __restrict__ xyz,
                                                  int* __restrict__ out_idx)
{
    int b = blockIdx.x;
    __shared__ float sx[N], sy[N], sz[N], sd[N];
    __shared__ float rval[256];
    __shared__ int   ridx[256];
    __shared__ int   sfar;
    const float* p = xyz + (size_t)b * N * 3;
    for (int i = threadIdx.x; i < N; i += 256) {
        sx[i] = p[i*3+0];
        sy[i] = p[i*3+1];
        sz[i] = p[i*3+2];
        sd[i] = 1e10f;
    }
    if (threadIdx.x == 0) sfar = 0;
    __syncthreads();
    for (int s = 0; s < M; ++s) {
        int far = sfar;
        if (threadIdx.x == 0) out_idx[(size_t)b*M + s] = far;
        float cx = sx[far], cy = sy[far], cz = sz[far];
        float best = -1.0f; int besti = 0;
        for (int i = threadIdx.x; i < N; i += 256) {
            float dx = __fsub_rn(sx[i], cx);
            float dy = __fsub_rn(sy[i], cy);
            float dz = __fsub_rn(sz[i], cz);
            float d  = __fadd_rn(__fadd_rn(__fmul_rn(dx,dx), __fmul_rn(dy,dy)),
                                 __fmul_rn(dz,dz));
            float dd = fminf(sd[i], d);
            sd[i] = dd;
            if (dd > best) { best = dd; besti = i; }   // strict > keeps first occurrence
        }
        rval[threadIdx.x] = best; ridx[threadIdx.x] = besti;
        __syncthreads();
        for (int off = 128; off > 0; off >>= 1) {
            if (threadIdx.x < off) {
                float v2 = rval[threadIdx.x + off];
                int   i2 = ridx[threadIdx.x + off];
                float v1 = rval[threadIdx.x];
                int   i1 = ridx[threadIdx.x];
                if (v2 > v1 || (v2 == v1 && i2 < i1)) {
                    rval[threadIdx.x] = v2; ridx[threadIdx.x] = i2;
                }
            }
            __syncthreads();
        }
        if (threadIdx.x == 0) sfar = ridx[0];
        __syncthreads();
    }
}

// ---------------------------------------------------------------------------
// Ball query: one thread per centroid, scan points ascending, first K within
// radius, pad with first hit. Also writes new_xyz (gathered centroids).
// ---------------------------------------------------------------------------
__global__ void ballquery_kernel(const float* __restrict__ xyz, const int* __restrict__ fidx,
                                 float* __restrict__ new_xyz, int* __restrict__ gi,
                                 int B, int N, int M, int K, float r2)
{
    int t = blockIdx.x * blockDim.x + threadIdx.x;
    if (t >= B * M) return;
    int b = t / M;
    const float* p = xyz + (size_t)b * N * 3;
    int fi = fidx[t];
    float cx = p[fi*3+0], cy = p[fi*3+1], cz = p[fi*3+2];
    new_xyz[t*3+0] = cx; new_xyz[t*3+1] = cy; new_xyz[t*3+2] = cz;
    int* out = gi + (size_t)t * K;
    int cnt = 0, first = 0;
    bool havefirst = false;
    for (int i = 0; i < N; ++i) {
        float dx = __fsub_rn(p[i*3+0], cx);
        float dy = __fsub_rn(p[i*3+1], cy);
        float dz = __fsub_rn(p[i*3+2], cz);
        float d  = __fadd_rn(__fadd_rn(__fmul_rn(dx,dx), __fmul_rn(dy,dy)),
                             __fmul_rn(dz,dz));
        if (d <= r2) {
            if (!havefirst) { first = i; havefirst = true; }
            out[cnt++] = i;
            if (cnt == K) break;
        }
    }
    for (; cnt < K; ++cnt) out[cnt] = first;
}

// ---------------------------------------------------------------------------
// Fused set-abstraction MLP: one block per centroid. Stage grouped input in
// LDS, run 3 (1x1 conv + bias + relu) layers ping-ponging LDS buffers, then
// max-pool over the K neighbors. Weights read from global (L2-resident),
// each weight load reused across 4 neighbor rows.
// ---------------------------------------------------------------------------
template<int CI, int CO, int KPTS>
DEVFN void mlp_layer(const float* __restrict__ in, const float* __restrict__ w,
                     const float* __restrict__ bias, float* __restrict__ out)
{
    constexpr int KG = KPTS / 4;
    for (int t = threadIdx.x; t < KG * CO; t += blockDim.x) {
        int co = t % CO, kg = t / CO;
        const float* i0 = in + kg * 4 * CI;
        const float* wp = w + co;
        float bv = bias[co];
        float a0 = bv, a1 = bv, a2 = bv, a3 = bv;
        for (int ci = 0; ci < CI; ++ci) {
            float wv = wp[(size_t)ci * CO];
            a0 += i0[ci]        * wv;
            a1 += i0[CI + ci]   * wv;
            a2 += i0[2*CI + ci] * wv;
            a3 += i0[3*CI + ci] * wv;
        }
        float* o = out + kg * 4 * CO + co;
        o[0]     = fmaxf(a0, 0.f);
        o[CO]    = fmaxf(a1, 0.f);
        o[2*CO]  = fmaxf(a2, 0.f);
        o[3*CO]  = fmaxf(a3, 0.f);
    }
}

template<int KPTS, int CF, int C1, int C2, int C3>
__global__ __launch_bounds__(256) void sa_mlp_kernel(
    const float* __restrict__ xyz, const float* __restrict__ feats,
    const float* __restrict__ new_xyz, const int* __restrict__ gi,
    const float* __restrict__ w1, const float* __restrict__ b1,
    const float* __restrict__ w2, const float* __restrict__ b2,
    const float* __restrict__ w3, const float* __restrict__ b3,
    float* __restrict__ fout, int N, int M)
{
    constexpr int CIN = CF + 3;
    __shared__ float bufA[KPTS * (CIN > C2 ? CIN : C2)];
    __shared__ float bufB[KPTS * (C1 > C3 ? C1 : C3)];
    int bm = blockIdx.x;
    int b  = bm / M;
    const int* g = gi + (size_t)bm * KPTS;
    float cx = new_xyz[bm*3+0], cy = new_xyz[bm*3+1], cz = new_xyz[bm*3+2];
    for (int t = threadIdx.x; t < KPTS * CIN; t += blockDim.x) {
        int k = t / CIN, c = t % CIN;
        int idx = g[k];
        float v;
        if (c == 0)      v = __fsub_rn(xyz[((size_t)b*N + idx)*3 + 0], cx);
        else if (c == 1) v = __fsub_rn(xyz[((size_t)b*N + idx)*3 + 1], cy);
        else if (c == 2) v = __fsub_rn(xyz[((size_t)b*N + idx)*3 + 2], cz);
        else             v = feats[((size_t)b*N + idx)*CF + (c - 3)];
        bufA[t] = v;
    }
    __syncthreads();
    mlp_layer<CIN, C1, KPTS>(bufA, w1, b1, bufB);
    __syncthreads();
    mlp_layer<C1,  C2, KPTS>(bufB, w2, b2, bufA);
    __syncthreads();
    mlp_layer<C2,  C3, KPTS>(bufA, w3, b3, bufB);
    __syncthreads();
    for (int co = threadIdx.x; co < C3; co += blockDim.x) {
        float mx = bufB[co];
        for (int k = 1; k < KPTS; ++k) mx = fmaxf(mx, bufB[k*C3 + co]);
        fout[(size_t)bm * C3 + co] = mx;
    }
}

// ---------------------------------------------------------------------------
// concat [R,3] ++ [R,CF] -> [R,3+CF]
// ---------------------------------------------------------------------------
__global__ void concat_kernel(const float* __restrict__ a, const float* __restrict__ f,
                              float* __restrict__ out, int R, int CF)
{
    int C = CF + 3;
    int t = blockIdx.x * blockDim.x + threadIdx.x;
    if (t >= R * C) return;
    int r = t / C, c = t % C;
    out[t] = (c < 3) ? a[r*3 + c] : f[(size_t)r * CF + (c - 3)];
}

// ---------------------------------------------------------------------------
// Generic tiled fp32 GEMM: C = act(A[M,K] @ W[K,N] (+bias)). 64x64 tile,
// 256 threads, 4x4 register micro-tile, BK=16 with zero-padded tails.
// ---------------------------------------------------------------------------
template<int RELU, int HASB>
__global__ __launch_bounds__(256) void gemm_kernel(
    const float* __restrict__ A, const float* __restrict__ W,
    const float* __restrict__ bias, float* __restrict__ Cc,
    int Mr, int Nc, int Kd)
{
    __shared__ float As[64][17];
    __shared__ float Ws[16][65];
    int tx = threadIdx.x % 16;
    int ty = threadIdx.x / 16;
    int row0 = blockIdx.y * 64;
    int col0 = blockIdx.x * 64;
    float acc[4][4] = {};
    for (int k0 = 0; k0 < Kd; k0 += 16) {
        for (int t = threadIdx.x; t < 64*16; t += 256) {
            int r = t >> 4, kk = t & 15;
            int gr = row0 + r, gk = k0 + kk;
            As[r][kk] = (gr < Mr && gk < Kd) ? A[(size_t)gr * Kd + gk] : 0.f;
        }
        for (int t = threadIdx.x; t < 16*64; t += 256) {
            int kk = t >> 6, c = t & 63;
            int gk = k0 + kk, gc = col0 + c;
            Ws[kk][c] = (gk < Kd && gc < Nc) ? W[(size_t)gk * Nc + gc] : 0.f;
        }
        __syncthreads();
        #pragma unroll
        for (int kk = 0; kk < 16; ++kk) {
            float av[4], wv[4];
            #pragma unroll
            for (int i = 0; i < 4; i++) av[i] = As[ty*4+i][kk];
            #pragma unroll
            for (int j = 0; j < 4; j++) wv[j] = Ws[kk][tx*4+j];
            #pragma unroll
            for (int i = 0; i < 4; i++)
                #pragma unroll
                for (int j = 0; j < 4; j++)
                    acc[i][j] += av[i] * wv[j];
        }
        __syncthreads();
    }
    #pragma unroll
    for (int i = 0; i < 4; i++) {
        int gr = row0 + ty*4 + i;
        if (gr >= Mr) continue;
        #pragma unroll
        for (int j = 0; j < 4; j++) {
            int gc = col0 + tx*4 + j;
            if (gc >= Nc) continue;
            float v = acc[i][j];
            if (HASB) v += bias[gc];
            if (RELU) v = fmaxf(v, 0.f);
            Cc[(size_t)gr * Nc + gc] = v;
        }
    }
}

// ---------------------------------------------------------------------------
// Max over P points: in [B,P,C] -> out [B,C]
// ---------------------------------------------------------------------------
__global__ void rowmax_kernel(const float* __restrict__ in, float* __restrict__ out,
                              int B, int P, int C)
{
    int t = blockIdx.x * blockDim.x + threadIdx.x;
    if (t >= B * C) return;
    int b = t / C, c = t % C;
    const float* p = in + (size_t)b * P * C + c;
    float mx = p[0];
    for (int i = 1; i < P; ++i) mx = fmaxf(mx, p[(size_t)i * C]);
    out[t] = mx;
}

// ---------------------------------------------------------------------------
extern "C" void kernel_launch(void* const* d_in, const int* in_sizes, int n_in,
                              void* d_out, int out_size, void* d_ws, size_t ws_size,
                              hipStream_t stream)
{
    const float* xyz    = (const float*)d_in[0];
    const float* points = (const float*)d_in[1];
    const float* w1a = (const float*)d_in[2];  const float* b1a = (const float*)d_in[3];
    const float* w1b = (const float*)d_in[4];  const float* b1b = (const float*)d_in[5];
    const float* w1c = (const float*)d_in[6];  const float* b1c = (const float*)d_in[7];
    const float* w2a = (const float*)d_in[8];  const float* b2a = (const float*)d_in[9];
    const float* w2b = (const float*)d_in[10]; const float* b2b = (const float*)d_in[11];
    const float* w2c = (const float*)d_in[12]; const float* b2c = (const float*)d_in[13];
    const float* w3a = (const float*)d_in[14]; const float* b3a = (const float*)d_in[15];
    const float* w3b = (const float*)d_in[16]; const float* b3b = (const float*)d_in[17];
    const float* w3c = (const float*)d_in[18]; const float* b3c = (const float*)d_in[19];
    const float* lin1 = (const float*)d_in[20];
    const float* lin2 = (const float*)d_in[21];
    const float* clsw = (const float*)d_in[22];
    const float* clsb = (const float*)d_in[23];

    char* ws = (char*)d_ws;
    size_t off = 0;
    auto alloc = [&](size_t bytes) -> void* {
        void* p = ws + off;
        off += (bytes + 255) & ~(size_t)255;
        return p;
    };
    int*   fps1 = (int*)  alloc((size_t)32*512*4);
    float* nx1  = (float*)alloc((size_t)32*512*3*4);
    int*   gi1  = (int*)  alloc((size_t)32*512*32*4);
    float* f1   = (float*)alloc((size_t)32*512*128*4);
    int*   fps2 = (int*)  alloc((size_t)32*128*4);
    float* nx2  = (float*)alloc((size_t)32*128*3*4);
    int*   gi2  = (int*)  alloc((size_t)32*128*64*4);
    float* f2   = (float*)alloc((size_t)32*128*256*4);
    float* g3   = (float*)alloc((size_t)4096*259*4);
    float* h3a  = (float*)alloc((size_t)4096*256*4);
    float* h3b  = (float*)alloc((size_t)4096*512*4);
    float* h3c  = (float*)alloc((size_t)4096*1024*4);
    float* f3   = (float*)alloc((size_t)32*1024*4);
    float* fc1  = (float*)alloc((size_t)32*512*4);
    float* fc2  = (float*)alloc((size_t)32*256*4);

    // ---- SA1: N=1024 -> M=512, r=0.2, K=32, MLP 6->64->64->128
    fps_kernel<1024, 512><<<32, 256, 0, stream>>>(xyz, fps1);
    ballquery_kernel<<<ceil_div(32*512, 256), 256, 0, stream>>>(
        xyz, fps1, nx1, gi1, 32, 1024, 512, 32, (float)(0.2*0.2));
    sa_mlp_kernel<32, 3, 64, 64, 128><<<32*512, 256, 0, stream>>>(
        xyz, points, nx1, gi1, w1a, b1a, w1b, b1b, w1c, b1c, f1, 1024, 512);

    // ---- SA2: N=512 -> M=128, r=0.4, K=64, MLP 131->128->128->256
    fps_kernel<512, 128><<<32, 256, 0, stream>>>(nx1, fps2);
    ballquery_kernel<<<ceil_div(32*128, 256), 256, 0, stream>>>(
        nx1, fps2, nx2, gi2, 32, 512, 128, 64, (float)(0.4*0.4));
    sa_mlp_kernel<64, 128, 128, 128, 256><<<32*128, 256, 0, stream>>>(
        nx1, f1, nx2, gi2, w2a, b2a, w2b, b2b, w2c, b2c, f2, 512, 128);

    // ---- SA3 (group_all): concat [32*128, 259] -> MLP 259->256->512->1024 -> max over 128
    concat_kernel<<<ceil_div(4096*259, 256), 256, 0, stream>>>(nx2, f2, g3, 4096, 256);
    {
        dim3 g(ceil_div(256, 64), ceil_div(4096, 64));
        gemm_kernel<1,1><<<g, 256, 0, stream>>>(g3, w3a, b3a, h3a, 4096, 256, 259);
    }
    {
        dim3 g(ceil_div(512, 64), ceil_div(4096, 64));
        gemm_kernel<1,1><<<g, 256, 0, stream>>>(h3a, w3b, b3b, h3b, 4096, 512, 256);
    }
    {
        dim3 g(ceil_div(1024, 64), ceil_div(4096, 64));
        gemm_kernel<1,1><<<g, 256, 0, stream>>>(h3b, w3c, b3c, h3c, 4096, 1024, 512);
    }
    rowmax_kernel<<<ceil_div(32*1024, 256), 256, 0, stream>>>(h3c, f3, 32, 128, 1024);

    // ---- FC head
    {
        dim3 g(ceil_div(512, 64), 1);
        gemm_kernel<1,0><<<g, 256, 0, stream>>>(f3, lin1, nullptr, fc1, 32, 512, 1024);
    }
    {
        dim3 g(ceil_div(256, 64), 1);
        gemm_kernel<1,0><<<g, 256, 0, stream>>>(fc1, lin2, nullptr, fc2, 32, 256, 512);
    }
    {
        dim3 g(1, 1);
        gemm_kernel<0,1><<<g, 256, 0, stream>>>(fc2, clsw, clsb, (float*)d_out, 32, 40, 256);
    }
}

// Round 2
// 2455.277 us; speedup vs baseline: 1.5695x; 1.5695x over previous
//
#include <hip/hip_runtime.h>

#define DEVFN __device__ __forceinline__

static inline int ceil_div(int a, int b) { return (a + b - 1) / b; }

// ---------------------------------------------------------------------------
// Farthest point sampling. One block per batch, one THREAD per point.
// Own point coords + running min-dist in registers; argmax via wave shfl
// butterfly (first-occurrence tie-break) + tiny LDS cross-wave reduce.
// Also writes new_xyz (the gathered sampled centroids).
// Exact fp32 (no FMA contraction) to match the numpy reference bit-for-bit.
// ---------------------------------------------------------------------------
template<int N>
__global__ __launch_bounds__(1024) void fps_kernel(const float* __restrict__ xyz, int M,
                                                   int* __restrict__ out_idx,
                                                   float* __restrict__ nxout)
{
    constexpr int NW = N / 64;
    int b = blockIdx.x, tid = threadIdx.x;
    __shared__ float sx[N], sy[N], sz[N];
    __shared__ float swv[NW];
    __shared__ int   swi[NW];
    __shared__ int   sfar;
    const float* p = xyz + (size_t)b * N * 3;
    float mx = p[tid*3+0], my = p[tid*3+1], mz = p[tid*3+2];
    sx[tid] = mx; sy[tid] = my; sz[tid] = mz;
    float dd = 1e10f;
    if (tid == 0) sfar = 0;
    __syncthreads();
    for (int s = 0; s < M; ++s) {
        int far = sfar;
        float cx = sx[far], cy = sy[far], cz = sz[far];
        if (tid == 0) {
            out_idx[(size_t)b*M + s] = far;
            nxout[((size_t)b*M + s)*3 + 0] = cx;
            nxout[((size_t)b*M + s)*3 + 1] = cy;
            nxout[((size_t)b*M + s)*3 + 2] = cz;
        }
        float dx = __fsub_rn(mx, cx);
        float dy = __fsub_rn(my, cy);
        float dz = __fsub_rn(mz, cz);
        float d  = __fadd_rn(__fadd_rn(__fmul_rn(dx,dx), __fmul_rn(dy,dy)),
                             __fmul_rn(dz,dz));
        dd = fminf(dd, d);
        float v = dd; int bi = tid;
        #pragma unroll
        for (int o = 32; o > 0; o >>= 1) {
            float v2 = __shfl_xor(v, o);
            int   i2 = __shfl_xor(bi, o);
            if (v2 > v || (v2 == v && i2 < bi)) { v = v2; bi = i2; }
        }
        if ((tid & 63) == 0) { swv[tid >> 6] = v; swi[tid >> 6] = bi; }
        __syncthreads();
        if (tid < 64) {
            v  = (tid < NW) ? swv[tid] : -1.0f;
            bi = (tid < NW) ? swi[tid] : 0x7fffffff;
            #pragma unroll
            for (int o = NW/2; o > 0; o >>= 1) {
                float v2 = __shfl_xor(v, o);
                int   i2 = __shfl_xor(bi, o);
                if (v2 > v || (v2 == v && i2 < bi)) { v = v2; bi = i2; }
            }
            if (tid == 0) sfar = bi;
        }
        __syncthreads();
    }
}

// ---------------------------------------------------------------------------
// Ball query: one thread per centroid, scan points ascending, first K within
// radius, pad with first hit. new_xyz comes precomputed from fps_kernel.
// ---------------------------------------------------------------------------
__global__ void ballquery_kernel(const float* __restrict__ xyz,
                                 const float* __restrict__ new_xyz,
                                 int* __restrict__ gi,
                                 int B, int N, int M, int K, float r2)
{
    int t = blockIdx.x * blockDim.x + threadIdx.x;
    if (t >= B * M) return;
    int b = t / M;
    const float* p = xyz + (size_t)b * N * 3;
    float cx = new_xyz[t*3+0], cy = new_xyz[t*3+1], cz = new_xyz[t*3+2];
    int* out = gi + (size_t)t * K;
    int cnt = 0, first = 0;
    bool havefirst = false;
    for (int i = 0; i < N; ++i) {
        float dx = __fsub_rn(p[i*3+0], cx);
        float dy = __fsub_rn(p[i*3+1], cy);
        float dz = __fsub_rn(p[i*3+2], cz);
        float d  = __fadd_rn(__fadd_rn(__fmul_rn(dx,dx), __fmul_rn(dy,dy)),
                             __fmul_rn(dz,dz));
        if (d <= r2) {
            if (!havefirst) { first = i; havefirst = true; }
            out[cnt++] = i;
            if (cnt == K) break;
        }
    }
    for (; cnt < K; ++cnt) out[cnt] = first;
}

// ---------------------------------------------------------------------------
// Register-tiled MLP layer inside the fused SA kernel.
// in:  LDS [KPTS rows, stride IS], w: global [CI x CO], out: LDS [KPTS, stride OS]
// Thread grid: (KPTS/TM) k-groups x (CO/TN) co-groups == 256 threads.
// Per ci: TM LDS broadcasts + TN global weight loads -> TM*TN FMAs.
// ---------------------------------------------------------------------------
template<int CI, int IS, int CO, int OS, int KPTS, int TM, int TN>
DEVFN void layer(const float* __restrict__ in, const float* __restrict__ w,
                 const float* __restrict__ bias, float* __restrict__ out)
{
    constexpr int CG = CO / TN;
    static_assert((KPTS / TM) * CG == 256, "thread grid");
    int cg = threadIdx.x % CG;
    int kg = threadIdx.x / CG;
    const float* ip = in + kg * TM * IS;
    const float* wp = w + cg * TN;
    float acc[TM][TN];
    float bv[TN];
    #pragma unroll
    for (int j = 0; j < TN; j++) bv[j] = bias[cg*TN + j];
    #pragma unroll
    for (int i = 0; i < TM; i++)
        #pragma unroll
        for (int j = 0; j < TN; j++) acc[i][j] = bv[j];
    #pragma unroll 4
    for (int ci = 0; ci < CI; ++ci) {
        float wv[TN];
        #pragma unroll
        for (int j = 0; j < TN; j++) wv[j] = wp[(size_t)ci * CO + j];
        float av[TM];
        #pragma unroll
        for (int i = 0; i < TM; i++) av[i] = ip[i*IS + ci];
        #pragma unroll
        for (int i = 0; i < TM; i++)
            #pragma unroll
            for (int j = 0; j < TN; j++) acc[i][j] += av[i] * wv[j];
    }
    float* op = out + kg * TM * OS + cg * TN;
    #pragma unroll
    for (int i = 0; i < TM; i++)
        #pragma unroll
        for (int j = 0; j < TN; j++) op[i*OS + j] = fmaxf(acc[i][j], 0.f);
}

// Same but fused with max over the k rows: writes partial-max [KPTS/TM][CO].
template<int CI, int IS, int CO, int KPTS, int TM, int TN>
DEVFN void layer_max(const float* __restrict__ in, const float* __restrict__ w,
                     const float* __restrict__ bias, float* __restrict__ partial)
{
    constexpr int CG = CO / TN;
    static_assert((KPTS / TM) * CG == 256, "thread grid");
    int cg = threadIdx.x % CG;
    int kg = threadIdx.x / CG;
    const float* ip = in + kg * TM * IS;
    const float* wp = w + cg * TN;
    float acc[TM][TN];
    float bv[TN];
    #pragma unroll
    for (int j = 0; j < TN; j++) bv[j] = bias[cg*TN + j];
    #pragma unroll
    for (int i = 0; i < TM; i++)
        #pragma unroll
        for (int j = 0; j < TN; j++) acc[i][j] = bv[j];
    #pragma unroll 4
    for (int ci = 0; ci < CI; ++ci) {
        float wv[TN];
        #pragma unroll
        for (int j = 0; j < TN; j++) wv[j] = wp[(size_t)ci * CO + j];
        float av[TM];
        #pragma unroll
        for (int i = 0; i < TM; i++) av[i] = ip[i*IS + ci];
        #pragma unroll
        for (int i = 0; i < TM; i++)
            #pragma unroll
            for (int j = 0; j < TN; j++) acc[i][j] += av[i] * wv[j];
    }
    #pragma unroll
    for (int j = 0; j < TN; j++) {
        float m = acc[0][j];
        #pragma unroll
        for (int i = 1; i < TM; i++) m = fmaxf(m, acc[i][j]);
        partial[kg*CO + cg*TN + j] = fmaxf(m, 0.f);   // relu(max) == max(relu)
    }
}

// ---------------------------------------------------------------------------
// Fused set-abstraction MLP: one block per centroid. Grouped input staged in
// LDS, 3 layers ping-ponging LDS (padded strides to dodge bank conflicts),
// max-pool fused into layer 3 (partial max + small LDS reduce).
// ---------------------------------------------------------------------------
template<int KPTS, int CF, int C1, int C2, int C3,
         int TM1, int TN1, int TM2, int TN2, int TM3, int TN3>
__global__ __launch_bounds__(256, 2) void sa_mlp_kernel(
    const float* __restrict__ xyz, const float* __restrict__ feats,
    const float* __restrict__ new_xyz, const int* __restrict__ gi,
    const float* __restrict__ w1, const float* __restrict__ b1,
    const float* __restrict__ w2, const float* __restrict__ b2,
    const float* __restrict__ w3, const float* __restrict__ b3,
    float* __restrict__ fout, int N, int M)
{
    constexpr int CIN = CF + 3;
    constexpr int S1  = C1 + 1;               // padded LDS strides
    constexpr int S2  = C2 + 1;
    constexpr int KG3 = KPTS / TM3;
    constexpr int ASZ = (KPTS*CIN > KPTS*S2) ? KPTS*CIN : KPTS*S2;
    constexpr int BSZ = (KPTS*S1 > KG3*C3) ? KPTS*S1 : KG3*C3;
    __shared__ float bufA[ASZ];
    __shared__ float bufB[BSZ];
    __shared__ int   sgi[KPTS];
    int bm = blockIdx.x;
    int b  = bm / M;
    if (threadIdx.x < KPTS) sgi[threadIdx.x] = gi[(size_t)bm * KPTS + threadIdx.x];
    float cx = new_xyz[bm*3+0], cy = new_xyz[bm*3+1], cz = new_xyz[bm*3+2];
    __syncthreads();
    for (int t = threadIdx.x; t < KPTS * CIN; t += 256) {
        int k = t / CIN, c = t % CIN;
        int idx = sgi[k];
        float v;
        if (c == 0)      v = __fsub_rn(xyz[((size_t)b*N + idx)*3 + 0], cx);
        else if (c == 1) v = __fsub_rn(xyz[((size_t)b*N + idx)*3 + 1], cy);
        else if (c == 2) v = __fsub_rn(xyz[((size_t)b*N + idx)*3 + 2], cz);
        else             v = feats[((size_t)b*N + idx)*CF + (c - 3)];
        bufA[t] = v;
    }
    __syncthreads();
    layer<CIN, CIN, C1, S1, KPTS, TM1, TN1>(bufA, w1, b1, bufB);
    __syncthreads();
    layer<C1, S1, C2, S2, KPTS, TM2, TN2>(bufB, w2, b2, bufA);
    __syncthreads();
    layer_max<C2, S2, C3, KPTS, TM3, TN3>(bufA, w3, b3, bufB);
    __syncthreads();
    for (int c = threadIdx.x; c < C3; c += 256) {
        float m = bufB[c];
        #pragma unroll
        for (int g = 1; g < KG3; g++) m = fmaxf(m, bufB[g*C3 + c]);
        fout[(size_t)bm * C3 + c] = m;
    }
}

// ---------------------------------------------------------------------------
// concat [R,3] ++ [R,CF] -> [R,3+CF]
// ---------------------------------------------------------------------------
__global__ void concat_kernel(const float* __restrict__ a, const float* __restrict__ f,
                              float* __restrict__ out, int R, int CF)
{
    int C = CF + 3;
    int t = blockIdx.x * blockDim.x + threadIdx.x;
    if (t >= R * C) return;
    int r = t / C, c = t % C;
    out[t] = (c < 3) ? a[r*3 + c] : f[(size_t)r * CF + (c - 3)];
}

// ---------------------------------------------------------------------------
// Tiled fp32 GEMM, 64x64 tile / 4x4 micro (small shapes + FC head).
// ---------------------------------------------------------------------------
template<int RELU, int HASB>
__global__ __launch_bounds__(256) void gemm_kernel(
    const float* __restrict__ A, const float* __restrict__ W,
    const float* __restrict__ bias, float* __restrict__ Cc,
    int Mr, int Nc, int Kd)
{
    __shared__ float As[64][17];
    __shared__ float Ws[16][65];
    int tx = threadIdx.x % 16;
    int ty = threadIdx.x / 16;
    int row0 = blockIdx.y * 64;
    int col0 = blockIdx.x * 64;
    float acc[4][4] = {};
    for (int k0 = 0; k0 < Kd; k0 += 16) {
        for (int t = threadIdx.x; t < 64*16; t += 256) {
            int r = t >> 4, kk = t & 15;
            int gr = row0 + r, gk = k0 + kk;
            As[r][kk] = (gr < Mr && gk < Kd) ? A[(size_t)gr * Kd + gk] : 0.f;
        }
        for (int t = threadIdx.x; t < 16*64; t += 256) {
            int kk = t >> 6, c = t & 63;
            int gk = k0 + kk, gc = col0 + c;
            Ws[kk][c] = (gk < Kd && gc < Nc) ? W[(size_t)gk * Nc + gc] : 0.f;
        }
        __syncthreads();
        #pragma unroll
        for (int kk = 0; kk < 16; ++kk) {
            float av[4], wv[4];
            #pragma unroll
            for (int i = 0; i < 4; i++) av[i] = As[ty*4+i][kk];
            #pragma unroll
            for (int j = 0; j < 4; j++) wv[j] = Ws[kk][tx*4+j];
            #pragma unroll
            for (int i = 0; i < 4; i++)
                #pragma unroll
                for (int j = 0; j < 4; j++)
                    acc[i][j] += av[i] * wv[j];
        }
        __syncthreads();
    }
    #pragma unroll
    for (int i = 0; i < 4; i++) {
        int gr = row0 + ty*4 + i;
        if (gr >= Mr) continue;
        #pragma unroll
        for (int j = 0; j < 4; j++) {
            int gc = col0 + tx*4 + j;
            if (gc >= Nc) continue;
            float v = acc[i][j];
            if (HASB) v += bias[gc];
            if (RELU) v = fmaxf(v, 0.f);
            Cc[(size_t)gr * Nc + gc] = v;
        }
    }
}

// ---------------------------------------------------------------------------
// Tiled fp32 GEMM, 128x128 tile / 8x8 micro (strided fragment mapping, no
// bank conflicts) for the big SA3 GEMMs. Requires Mr%? handled by guards.
// ---------------------------------------------------------------------------
template<int RELU, int HASB>
__global__ __launch_bounds__(256, 2) void gemm128_kernel(
    const float* __restrict__ A, const float* __restrict__ W,
    const float* __restrict__ bias, float* __restrict__ Cc,
    int Mr, int Nc, int Kd)
{
    __shared__ float As[128][17];
    __shared__ float Ws[16][132];
    int tx = threadIdx.x % 16;
    int ty = threadIdx.x / 16;
    int row0 = blockIdx.y * 128;
    int col0 = blockIdx.x * 128;
    float acc[8][8] = {};
    for (int k0 = 0; k0 < Kd; k0 += 16) {
        for (int t = threadIdx.x; t < 128*16; t += 256) {
            int r = t >> 4, kk = t & 15;
            int gr = row0 + r, gk = k0 + kk;
            As[r][kk] = (gr < Mr && gk < Kd) ? A[(size_t)gr * Kd + gk] : 0.f;
        }
        for (int t = threadIdx.x; t < 16*128; t += 256) {
            int kk = t >> 7, c = t & 127;
            int gk = k0 + kk, gc = col0 + c;
            Ws[kk][c] = (gk < Kd && gc < Nc) ? W[(size_t)gk * Nc + gc] : 0.f;
        }
        __syncthreads();
        #pragma unroll
        for (int kk = 0; kk < 16; ++kk) {
            float av[8], wv[8];
            #pragma unroll
            for (int i = 0; i < 8; i++) av[i] = As[ty + 16*i][kk];
            #pragma unroll
            for (int j = 0; j < 8; j++) wv[j] = Ws[kk][tx + 16*j];
            #pragma unroll
            for (int i = 0; i < 8; i++)
                #pragma unroll
                for (int j = 0; j < 8; j++)
                    acc[i][j] += av[i] * wv[j];
        }
        __syncthreads();
    }
    #pragma unroll
    for (int i = 0; i < 8; i++) {
        int gr = row0 + ty + 16*i;
        if (gr >= Mr) continue;
        #pragma unroll
        for (int j = 0; j < 8; j++) {
            int gc = col0 + tx + 16*j;
            if (gc >= Nc) continue;
            float v = acc[i][j];
            if (HASB) v += bias[gc];
            if (RELU) v = fmaxf(v, 0.f);
            Cc[(size_t)gr * Nc + gc] = v;
        }
    }
}

// ---------------------------------------------------------------------------
// Max over P points: in [B,P,C] -> out [B,C]
// ---------------------------------------------------------------------------
__global__ void rowmax_kernel(const float* __restrict__ in, float* __restrict__ out,
                              int B, int P, int C)
{
    int t = blockIdx.x * blockDim.x + threadIdx.x;
    if (t >= B * C) return;
    int b = t / C, c = t % C;
    const float* p = in + (size_t)b * P * C + c;
    float mx = p[0];
    for (int i = 1; i < P; ++i) mx = fmaxf(mx, p[(size_t)i * C]);
    out[t] = mx;
}

// ---------------------------------------------------------------------------
extern "C" void kernel_launch(void* const* d_in, const int* in_sizes, int n_in,
                              void* d_out, int out_size, void* d_ws, size_t ws_size,
                              hipStream_t stream)
{
    const float* xyz    = (const float*)d_in[0];
    const float* points = (const float*)d_in[1];
    const float* w1a = (const float*)d_in[2];  const float* b1a = (const float*)d_in[3];
    const float* w1b = (const float*)d_in[4];  const float* b1b = (const float*)d_in[5];
    const float* w1c = (const float*)d_in[6];  const float* b1c = (const float*)d_in[7];
    const float* w2a = (const float*)d_in[8];  const float* b2a = (const float*)d_in[9];
    const float* w2b = (const float*)d_in[10]; const float* b2b = (const float*)d_in[11];
    const float* w2c = (const float*)d_in[12]; const float* b2c = (const float*)d_in[13];
    const float* w3a = (const float*)d_in[14]; const float* b3a = (const float*)d_in[15];
    const float* w3b = (const float*)d_in[16]; const float* b3b = (const float*)d_in[17];
    const float* w3c = (const float*)d_in[18]; const float* b3c = (const float*)d_in[19];
    const float* lin1 = (const float*)d_in[20];
    const float* lin2 = (const float*)d_in[21];
    const float* clsw = (const float*)d_in[22];
    const float* clsb = (const float*)d_in[23];

    char* ws = (char*)d_ws;
    size_t off = 0;
    auto alloc = [&](size_t bytes) -> void* {
        void* p = ws + off;
        off += (bytes + 255) & ~(size_t)255;
        return p;
    };
    int*   fps1 = (int*)  alloc((size_t)32*512*4);
    float* nx1  = (float*)alloc((size_t)32*512*3*4);
    int*   gi1  = (int*)  alloc((size_t)32*512*32*4);
    float* f1   = (float*)alloc((size_t)32*512*128*4);
    int*   fps2 = (int*)  alloc((size_t)32*128*4);
    float* nx2  = (float*)alloc((size_t)32*128*3*4);
    int*   gi2  = (int*)  alloc((size_t)32*128*64*4);
    float* f2   = (float*)alloc((size_t)32*128*256*4);
    float* g3   = (float*)alloc((size_t)4096*259*4);
    float* h3a  = (float*)alloc((size_t)4096*256*4);
    float* h3b  = (float*)alloc((size_t)4096*512*4);
    float* h3c  = (float*)alloc((size_t)4096*1024*4);
    float* f3   = (float*)alloc((size_t)32*1024*4);
    float* fc1  = (float*)alloc((size_t)32*512*4);
    float* fc2  = (float*)alloc((size_t)32*256*4);

    // ---- SA1: N=1024 -> M=512, r=0.2, K=32, MLP 6->64->64->128
    fps_kernel<1024><<<32, 1024, 0, stream>>>(xyz, 512, fps1, nx1);
    ballquery_kernel<<<ceil_div(32*512, 256), 256, 0, stream>>>(
        xyz, nx1, gi1, 32, 1024, 512, 32, (float)(0.2*0.2));
    sa_mlp_kernel<32, 3, 64, 64, 128, 2,4, 2,4, 4,4><<<32*512, 256, 0, stream>>>(
        xyz, points, nx1, gi1, w1a, b1a, w1b, b1b, w1c, b1c, f1, 1024, 512);

    // ---- SA2: N=512 -> M=128, r=0.4, K=64, MLP 131->128->128->256
    fps_kernel<512><<<32, 512, 0, stream>>>(nx1, 128, fps2, nx2);
    ballquery_kernel<<<ceil_div(32*128, 256), 256, 0, stream>>>(
        nx1, nx2, gi2, 32, 512, 128, 64, (float)(0.4*0.4));
    sa_mlp_kernel<64, 128, 128, 128, 256, 4,8, 4,8, 8,8><<<32*128, 256, 0, stream>>>(
        nx1, f1, nx2, gi2, w2a, b2a, w2b, b2b, w2c, b2c, f2, 512, 128);

    // ---- SA3 (group_all): concat [4096, 259] -> MLP 259->256->512->1024 -> max over 128
    concat_kernel<<<ceil_div(4096*259, 256), 256, 0, stream>>>(nx2, f2, g3, 4096, 256);
    {
        dim3 g(ceil_div(256, 64), ceil_div(4096, 64));
        gemm_kernel<1,1><<<g, 256, 0, stream>>>(g3, w3a, b3a, h3a, 4096, 256, 259);
    }
    {
        dim3 g(ceil_div(512, 128), ceil_div(4096, 128));
        gemm128_kernel<1,1><<<g, 256, 0, stream>>>(h3a, w3b, b3b, h3b, 4096, 512, 256);
    }
    {
        dim3 g(ceil_div(1024, 128), ceil_div(4096, 128));
        gemm128_kernel<1,1><<<g, 256, 0, stream>>>(h3b, w3c, b3c, h3c, 4096, 1024, 512);
    }
    rowmax_kernel<<<ceil_div(32*1024, 256), 256, 0, stream>>>(h3c, f3, 32, 128, 1024);

    // ---- FC head
    {
        dim3 g(ceil_div(512, 64), 1);
        gemm_kernel<1,0><<<g, 256, 0, stream>>>(f3, lin1, nullptr, fc1, 32, 512, 1024);
    }
    {
        dim3 g(ceil_div(256, 64), 1);
        gemm_kernel<1,0><<<g, 256, 0, stream>>>(fc1, lin2, nullptr, fc2, 32, 256, 512);
    }
    {
        dim3 g(1, 1);
        gemm_kernel<0,1><<<g, 256, 0, stream>>>(fc2, clsw, clsb, (float*)d_out, 32, 40, 256);
    }
}

// Round 3
// 2432.283 us; speedup vs baseline: 1.5843x; 1.0095x over previous
//
#include <hip/hip_runtime.h>

#define DEVFN __device__ __forceinline__

static inline int ceil_div(int a, int b) { return (a + b - 1) / b; }

// ---------------------------------------------------------------------------
// Farthest point sampling — SINGLE WAVE per batch. 64 lanes, N/64 points per
// lane held in registers (coords + running min-dist). Per step: distance
// update in registers, shfl-xor butterfly argmax (first-occurrence
// tie-break), no __syncthreads in the loop. Coords of the running centroid
// come from an LDS copy via uniform-address broadcast reads.
// Exact fp32 (no FMA contraction) to match the numpy reference bit-for-bit.
// ---------------------------------------------------------------------------
template<int N>
__global__ __launch_bounds__(64) void fps_kernel(const float* __restrict__ xyz, int M,
                                                 int* __restrict__ out_idx,
                                                 float* __restrict__ nxout)
{
    constexpr int PPL = N / 64;
    int b = blockIdx.x, lane = threadIdx.x;
    __shared__ float sx[N], sy[N], sz[N];
    const float* p = xyz + (size_t)b * N * 3;
    float px[PPL], py[PPL], pz[PPL], dd[PPL];
    #pragma unroll
    for (int j = 0; j < PPL; ++j) {
        int idx = lane + 64 * j;
        px[j] = p[idx*3+0]; py[j] = p[idx*3+1]; pz[j] = p[idx*3+2];
        sx[idx] = px[j]; sy[idx] = py[j]; sz[idx] = pz[j];
        dd[j] = 1e10f;
    }
    __syncthreads();
    int far = 0;
    for (int s = 0; s < M; ++s) {
        float cx = sx[far], cy = sy[far], cz = sz[far];
        if (lane == 0) {
            out_idx[(size_t)b*M + s] = far;
            nxout[((size_t)b*M + s)*3 + 0] = cx;
            nxout[((size_t)b*M + s)*3 + 1] = cy;
            nxout[((size_t)b*M + s)*3 + 2] = cz;
        }
        float best = -1.0f; int bi = 0;
        #pragma unroll
        for (int j = 0; j < PPL; ++j) {
            float dx = __fsub_rn(px[j], cx);
            float dy = __fsub_rn(py[j], cy);
            float dz = __fsub_rn(pz[j], cz);
            float d  = __fadd_rn(__fadd_rn(__fmul_rn(dx,dx), __fmul_rn(dy,dy)),
                                 __fmul_rn(dz,dz));
            float nd = fminf(dd[j], d);
            dd[j] = nd;
            if (nd > best) { best = nd; bi = lane + 64*j; }  // strict >: first occurrence
        }
        #pragma unroll
        for (int o = 32; o > 0; o >>= 1) {
            float v2 = __shfl_xor(best, o);
            int   i2 = __shfl_xor(bi, o);
            if (v2 > best || (v2 == best && i2 < bi)) { best = v2; bi = i2; }
        }
        far = bi;   // uniform across the wave
    }
}

// ---------------------------------------------------------------------------
// Ball query: one thread per centroid, scan points ascending, first K within
// radius, pad with first hit. new_xyz comes precomputed from fps_kernel.
// ---------------------------------------------------------------------------
__global__ void ballquery_kernel(const float* __restrict__ xyz,
                                 const float* __restrict__ new_xyz,
                                 int* __restrict__ gi,
                                 int B, int N, int M, int K, float r2)
{
    int t = blockIdx.x * blockDim.x + threadIdx.x;
    if (t >= B * M) return;
    int b = t / M;
    const float* p = xyz + (size_t)b * N * 3;
    float cx = new_xyz[t*3+0], cy = new_xyz[t*3+1], cz = new_xyz[t*3+2];
    int* out = gi + (size_t)t * K;
    int cnt = 0, first = 0;
    bool havefirst = false;
    for (int i = 0; i < N; ++i) {
        float dx = __fsub_rn(p[i*3+0], cx);
        float dy = __fsub_rn(p[i*3+1], cy);
        float dz = __fsub_rn(p[i*3+2], cz);
        float d  = __fadd_rn(__fadd_rn(__fmul_rn(dx,dx), __fmul_rn(dy,dy)),
                             __fmul_rn(dz,dz));
        if (d <= r2) {
            if (!havefirst) { first = i; havefirst = true; }
            out[cnt++] = i;
            if (cnt == K) break;
        }
    }
    for (; cnt < K; ++cnt) out[cnt] = first;
}

// ---------------------------------------------------------------------------
// Register-tiled MLP layer. kg-FAST / cg-SLOW mapping: weight addresses are
// uniform within each KG-lane cluster (few distinct cache lines per wave);
// LDS fragment reads are 2-way-at-worst bank aliased (free). Weights loaded
// as float4; ci loop fully unrolled so the scheduler hoists loads early.
// ---------------------------------------------------------------------------
template<int CI, int IS, int CO, int OS, int KPTS, int TM, int TN>
DEVFN void layer(const float* __restrict__ in, const float* __restrict__ w,
                 const float* __restrict__ bias, float* __restrict__ out)
{
    constexpr int KG = KPTS / TM;
    constexpr int CG = CO / TN;
    constexpr int NV = TN / 4;
    static_assert(KG * CG == 256, "thread grid");
    static_assert(TN % 4 == 0, "float4 weights");
    const int kg = threadIdx.x % KG;
    const int cg = threadIdx.x / KG;
    const float* ip = in + kg * TM * IS;
    const float* wp = w + cg * TN;
    float acc[TM][TN];
    #pragma unroll
    for (int v = 0; v < NV; ++v) {
        float4 bv = *(const float4*)(bias + cg*TN + 4*v);
        #pragma unroll
        for (int i = 0; i < TM; ++i) {
            acc[i][4*v+0] = bv.x; acc[i][4*v+1] = bv.y;
            acc[i][4*v+2] = bv.z; acc[i][4*v+3] = bv.w;
        }
    }
    #pragma unroll
    for (int ci = 0; ci < CI; ++ci) {
        float4 wv[NV];
        #pragma unroll
        for (int v = 0; v < NV; ++v) wv[v] = *(const float4*)(wp + ci*CO + 4*v);
        float av[TM];
        #pragma unroll
        for (int i = 0; i < TM; ++i) av[i] = ip[i*IS + ci];
        #pragma unroll
        for (int i = 0; i < TM; ++i)
            #pragma unroll
            for (int v = 0; v < NV; ++v) {
                acc[i][4*v+0] += av[i] * wv[v].x;
                acc[i][4*v+1] += av[i] * wv[v].y;
                acc[i][4*v+2] += av[i] * wv[v].z;
                acc[i][4*v+3] += av[i] * wv[v].w;
            }
    }
    float* op = out + kg * TM * OS + cg * TN;
    #pragma unroll
    for (int i = 0; i < TM; ++i)
        #pragma unroll
        for (int j = 0; j < TN; ++j) op[i*OS + j] = fmaxf(acc[i][j], 0.f);
}

// Same but fused with max over the TM rows: writes partial-max [KPTS/TM][CO].
template<int CI, int IS, int CO, int KPTS, int TM, int TN>
DEVFN void layer_max(const float* __restrict__ in, const float* __restrict__ w,
                     const float* __restrict__ bias, float* __restrict__ partial)
{
    constexpr int KG = KPTS / TM;
    constexpr int CG = CO / TN;
    constexpr int NV = TN / 4;
    static_assert(KG * CG == 256, "thread grid");
    const int kg = threadIdx.x % KG;
    const int cg = threadIdx.x / KG;
    const float* ip = in + kg * TM * IS;
    const float* wp = w + cg * TN;
    float acc[TM][TN];
    #pragma unroll
    for (int v = 0; v < NV; ++v) {
        float4 bv = *(const float4*)(bias + cg*TN + 4*v);
        #pragma unroll
        for (int i = 0; i < TM; ++i) {
            acc[i][4*v+0] = bv.x; acc[i][4*v+1] = bv.y;
            acc[i][4*v+2] = bv.z; acc[i][4*v+3] = bv.w;
        }
    }
    #pragma unroll
    for (int ci = 0; ci < CI; ++ci) {
        float4 wv[NV];
        #pragma unroll
        for (int v = 0; v < NV; ++v) wv[v] = *(const float4*)(wp + ci*CO + 4*v);
        float av[TM];
        #pragma unroll
        for (int i = 0; i < TM; ++i) av[i] = ip[i*IS + ci];
        #pragma unroll
        for (int i = 0; i < TM; ++i)
            #pragma unroll
            for (int v = 0; v < NV; ++v) {
                acc[i][4*v+0] += av[i] * wv[v].x;
                acc[i][4*v+1] += av[i] * wv[v].y;
                acc[i][4*v+2] += av[i] * wv[v].z;
                acc[i][4*v+3] += av[i] * wv[v].w;
            }
    }
    #pragma unroll
    for (int j = 0; j < TN; ++j) {
        float m = acc[0][j];
        #pragma unroll
        for (int i = 1; i < TM; ++i) m = fmaxf(m, acc[i][j]);
        partial[kg*CO + cg*TN + j] = fmaxf(m, 0.f);   // relu(max) == max(relu)
    }
}

// ---------------------------------------------------------------------------
// Fused set-abstraction MLP: one block per centroid. Grouped input staged in
// LDS, 3 layers ping-ponging LDS (odd strides, conflicts analyzed free),
// max-pool fused into layer 3 (partial max + small LDS reduce).
// ---------------------------------------------------------------------------
template<int KPTS, int CF, int C1, int C2, int C3,
         int TM1, int TN1, int TM2, int TN2, int TM3, int TN3>
__global__ __launch_bounds__(256, 2) void sa_mlp_kernel(
    const float* __restrict__ xyz, const float* __restrict__ feats,
    const float* __restrict__ new_xyz, const int* __restrict__ gi,
    const float* __restrict__ w1, const float* __restrict__ b1,
    const float* __restrict__ w2, const float* __restrict__ b2,
    const float* __restrict__ w3, const float* __restrict__ b3,
    float* __restrict__ fout, int N, int M)
{
    constexpr int CIN = CF + 3;
    constexpr int S1  = C1 + 1;               // odd LDS strides
    constexpr int S2  = C2 + 1;
    constexpr int KG3 = KPTS / TM3;
    constexpr int ASZ = (KPTS*CIN > KPTS*S2) ? KPTS*CIN : KPTS*S2;
    constexpr int BSZ = (KPTS*S1 > KG3*C3) ? KPTS*S1 : KG3*C3;
    __shared__ float bufA[ASZ];
    __shared__ float bufB[BSZ];
    __shared__ int   sgi[KPTS];
    int bm = blockIdx.x;
    int b  = bm / M;
    if (threadIdx.x < KPTS) sgi[threadIdx.x] = gi[(size_t)bm * KPTS + threadIdx.x];
    float cx = new_xyz[bm*3+0], cy = new_xyz[bm*3+1], cz = new_xyz[bm*3+2];
    __syncthreads();
    for (int t = threadIdx.x; t < KPTS * CIN; t += 256) {
        int k = t / CIN, c = t % CIN;
        int idx = sgi[k];
        float v;
        if (c == 0)      v = __fsub_rn(xyz[((size_t)b*N + idx)*3 + 0], cx);
        else if (c == 1) v = __fsub_rn(xyz[((size_t)b*N + idx)*3 + 1], cy);
        else if (c == 2) v = __fsub_rn(xyz[((size_t)b*N + idx)*3 + 2], cz);
        else             v = feats[((size_t)b*N + idx)*CF + (c - 3)];
        bufA[t] = v;
    }
    __syncthreads();
    layer<CIN, CIN, C1, S1, KPTS, TM1, TN1>(bufA, w1, b1, bufB);
    __syncthreads();
    layer<C1, S1, C2, S2, KPTS, TM2, TN2>(bufB, w2, b2, bufA);
    __syncthreads();
    layer_max<C2, S2, C3, KPTS, TM3, TN3>(bufA, w3, b3, bufB);
    __syncthreads();
    for (int c = threadIdx.x; c < C3; c += 256) {
        float m = bufB[c];
        #pragma unroll
        for (int g = 1; g < KG3; g++) m = fmaxf(m, bufB[g*C3 + c]);
        fout[(size_t)bm * C3 + c] = m;
    }
}

// ---------------------------------------------------------------------------
// concat [R,3] ++ [R,CF] -> [R,3+CF]
// ---------------------------------------------------------------------------
__global__ void concat_kernel(const float* __restrict__ a, const float* __restrict__ f,
                              float* __restrict__ out, int R, int CF)
{
    int C = CF + 3;
    int t = blockIdx.x * blockDim.x + threadIdx.x;
    if (t >= R * C) return;
    int r = t / C, c = t % C;
    out[t] = (c < 3) ? a[r*3 + c] : f[(size_t)r * CF + (c - 3)];
}

// ---------------------------------------------------------------------------
// Tiled fp32 GEMM, 64x64 tile / 4x4 micro (small shapes + FC head).
// ---------------------------------------------------------------------------
template<int RELU, int HASB>
__global__ __launch_bounds__(256) void gemm_kernel(
    const float* __restrict__ A, const float* __restrict__ W,
    const float* __restrict__ bias, float* __restrict__ Cc,
    int Mr, int Nc, int Kd)
{
    __shared__ float As[64][17];
    __shared__ float Ws[16][65];
    int tx = threadIdx.x % 16;
    int ty = threadIdx.x / 16;
    int row0 = blockIdx.y * 64;
    int col0 = blockIdx.x * 64;
    float acc[4][4] = {};
    for (int k0 = 0; k0 < Kd; k0 += 16) {
        for (int t = threadIdx.x; t < 64*16; t += 256) {
            int r = t >> 4, kk = t & 15;
            int gr = row0 + r, gk = k0 + kk;
            As[r][kk] = (gr < Mr && gk < Kd) ? A[(size_t)gr * Kd + gk] : 0.f;
        }
        for (int t = threadIdx.x; t < 16*64; t += 256) {
            int kk = t >> 6, c = t & 63;
            int gk = k0 + kk, gc = col0 + c;
            Ws[kk][c] = (gk < Kd && gc < Nc) ? W[(size_t)gk * Nc + gc] : 0.f;
        }
        __syncthreads();
        #pragma unroll
        for (int kk = 0; kk < 16; ++kk) {
            float av[4], wv[4];
            #pragma unroll
            for (int i = 0; i < 4; i++) av[i] = As[ty*4+i][kk];
            #pragma unroll
            for (int j = 0; j < 4; j++) wv[j] = Ws[kk][tx*4+j];
            #pragma unroll
            for (int i = 0; i < 4; i++)
                #pragma unroll
                for (int j = 0; j < 4; j++)
                    acc[i][j] += av[i] * wv[j];
        }
        __syncthreads();
    }
    #pragma unroll
    for (int i = 0; i < 4; i++) {
        int gr = row0 + ty*4 + i;
        if (gr >= Mr) continue;
        #pragma unroll
        for (int j = 0; j < 4; j++) {
            int gc = col0 + tx*4 + j;
            if (gc >= Nc) continue;
            float v = acc[i][j];
            if (HASB) v += bias[gc];
            if (RELU) v = fmaxf(v, 0.f);
            Cc[(size_t)gr * Nc + gc] = v;
        }
    }
}

// ---------------------------------------------------------------------------
// Tiled fp32 GEMM, 128x128 tile / 8x8 micro (strided fragment mapping).
// ---------------------------------------------------------------------------
template<int RELU, int HASB>
__global__ __launch_bounds__(256, 2) void gemm128_kernel(
    const float* __restrict__ A, const float* __restrict__ W,
    const float* __restrict__ bias, float* __restrict__ Cc,
    int Mr, int Nc, int Kd)
{
    __shared__ float As[128][17];
    __shared__ float Ws[16][132];
    int tx = threadIdx.x % 16;
    int ty = threadIdx.x / 16;
    int row0 = blockIdx.y * 128;
    int col0 = blockIdx.x * 128;
    float acc[8][8] = {};
    for (int k0 = 0; k0 < Kd; k0 += 16) {
        for (int t = threadIdx.x; t < 128*16; t += 256) {
            int r = t >> 4, kk = t & 15;
            int gr = row0 + r, gk = k0 + kk;
            As[r][kk] = (gr < Mr && gk < Kd) ? A[(size_t)gr * Kd + gk] : 0.f;
        }
        for (int t = threadIdx.x; t < 16*128; t += 256) {
            int kk = t >> 7, c = t & 127;
            int gk = k0 + kk, gc = col0 + c;
            Ws[kk][c] = (gk < Kd && gc < Nc) ? W[(size_t)gk * Nc + gc] : 0.f;
        }
        __syncthreads();
        #pragma unroll
        for (int kk = 0; kk < 16; ++kk) {
            float av[8], wv[8];
            #pragma unroll
            for (int i = 0; i < 8; i++) av[i] = As[ty + 16*i][kk];
            #pragma unroll
            for (int j = 0; j < 8; j++) wv[j] = Ws[kk][tx + 16*j];
            #pragma unroll
            for (int i = 0; i < 8; i++)
                #pragma unroll
                for (int j = 0; j < 8; j++)
                    acc[i][j] += av[i] * wv[j];
        }
        __syncthreads();
    }
    #pragma unroll
    for (int i = 0; i < 8; i++) {
        int gr = row0 + ty + 16*i;
        if (gr >= Mr) continue;
        #pragma unroll
        for (int j = 0; j < 8; j++) {
            int gc = col0 + tx + 16*j;
            if (gc >= Nc) continue;
            float v = acc[i][j];
            if (HASB) v += bias[gc];
            if (RELU) v = fmaxf(v, 0.f);
            Cc[(size_t)gr * Nc + gc] = v;
        }
    }
}

// ---------------------------------------------------------------------------
// Max over P points: in [B,P,C] -> out [B,C]
// ---------------------------------------------------------------------------
__global__ void rowmax_kernel(const float* __restrict__ in, float* __restrict__ out,
                              int B, int P, int C)
{
    int t = blockIdx.x * blockDim.x + threadIdx.x;
    if (t >= B * C) return;
    int b = t / C, c = t % C;
    const float* p = in + (size_t)b * P * C + c;
    float mx = p[0];
    for (int i = 1; i < P; ++i) mx = fmaxf(mx, p[(size_t)i * C]);
    out[t] = mx;
}

// ---------------------------------------------------------------------------
extern "C" void kernel_launch(void* const* d_in, const int* in_sizes, int n_in,
                              void* d_out, int out_size, void* d_ws, size_t ws_size,
                              hipStream_t stream)
{
    const float* xyz    = (const float*)d_in[0];
    const float* points = (const float*)d_in[1];
    const float* w1a = (const float*)d_in[2];  const float* b1a = (const float*)d_in[3];
    const float* w1b = (const float*)d_in[4];  const float* b1b = (const float*)d_in[5];
    const float* w1c = (const float*)d_in[6];  const float* b1c = (const float*)d_in[7];
    const float* w2a = (const float*)d_in[8];  const float* b2a = (const float*)d_in[9];
    const float* w2b = (const float*)d_in[10]; const float* b2b = (const float*)d_in[11];
    const float* w2c = (const float*)d_in[12]; const float* b2c = (const float*)d_in[13];
    const float* w3a = (const float*)d_in[14]; const float* b3a = (const float*)d_in[15];
    const float* w3b = (const float*)d_in[16]; const float* b3b = (const float*)d_in[17];
    const float* w3c = (const float*)d_in[18]; const float* b3c = (const float*)d_in[19];
    const float* lin1 = (const float*)d_in[20];
    const float* lin2 = (const float*)d_in[21];
    const float* clsw = (const float*)d_in[22];
    const float* clsb = (const float*)d_in[23];

    char* ws = (char*)d_ws;
    size_t off = 0;
    auto alloc = [&](size_t bytes) -> void* {
        void* p = ws + off;
        off += (bytes + 255) & ~(size_t)255;
        return p;
    };
    int*   fps1 = (int*)  alloc((size_t)32*512*4);
    float* nx1  = (float*)alloc((size_t)32*512*3*4);
    int*   gi1  = (int*)  alloc((size_t)32*512*32*4);
    float* f1   = (float*)alloc((size_t)32*512*128*4);
    int*   fps2 = (int*)  alloc((size_t)32*128*4);
    float* nx2  = (float*)alloc((size_t)32*128*3*4);
    int*   gi2  = (int*)  alloc((size_t)32*128*64*4);
    float* f2   = (float*)alloc((size_t)32*128*256*4);
    float* g3   = (float*)alloc((size_t)4096*259*4);
    float* h3a  = (float*)alloc((size_t)4096*256*4);
    float* h3b  = (float*)alloc((size_t)4096*512*4);
    float* h3c  = (float*)alloc((size_t)4096*1024*4);
    float* f3   = (float*)alloc((size_t)32*1024*4);
    float* fc1  = (float*)alloc((size_t)32*512*4);
    float* fc2  = (float*)alloc((size_t)32*256*4);

    // ---- SA1: N=1024 -> M=512, r=0.2, K=32, MLP 6->64->64->128
    fps_kernel<1024><<<32, 64, 0, stream>>>(xyz, 512, fps1, nx1);
    ballquery_kernel<<<ceil_div(32*512, 256), 256, 0, stream>>>(
        xyz, nx1, gi1, 32, 1024, 512, 32, (float)(0.2*0.2));
    sa_mlp_kernel<32, 3, 64, 64, 128, 2,4, 2,4, 4,4><<<32*512, 256, 0, stream>>>(
        xyz, points, nx1, gi1, w1a, b1a, w1b, b1b, w1c, b1c, f1, 1024, 512);

    // ---- SA2: N=512 -> M=128, r=0.4, K=64, MLP 131->128->128->256
    fps_kernel<512><<<32, 64, 0, stream>>>(nx1, 128, fps2, nx2);
    ballquery_kernel<<<ceil_div(32*128, 256), 256, 0, stream>>>(
        nx1, nx2, gi2, 32, 512, 128, 64, (float)(0.4*0.4));
    sa_mlp_kernel<64, 128, 128, 128, 256, 4,8, 4,8, 16,4><<<32*128, 256, 0, stream>>>(
        nx1, f1, nx2, gi2, w2a, b2a, w2b, b2b, w2c, b2c, f2, 512, 128);

    // ---- SA3 (group_all): concat [4096, 259] -> MLP 259->256->512->1024 -> max over 128
    concat_kernel<<<ceil_div(4096*259, 256), 256, 0, stream>>>(nx2, f2, g3, 4096, 256);
    {
        dim3 g(ceil_div(256, 64), ceil_div(4096, 64));
        gemm_kernel<1,1><<<g, 256, 0, stream>>>(g3, w3a, b3a, h3a, 4096, 256, 259);
    }
    {
        dim3 g(ceil_div(512, 128), ceil_div(4096, 128));
        gemm128_kernel<1,1><<<g, 256, 0, stream>>>(h3a, w3b, b3b, h3b, 4096, 512, 256);
    }
    {
        dim3 g(ceil_div(1024, 128), ceil_div(4096, 128));
        gemm128_kernel<1,1><<<g, 256, 0, stream>>>(h3b, w3c, b3c, h3c, 4096, 1024, 512);
    }
    rowmax_kernel<<<ceil_div(32*1024, 256), 256, 0, stream>>>(h3c, f3, 32, 128, 1024);

    // ---- FC head
    {
        dim3 g(ceil_div(512, 64), 1);
        gemm_kernel<1,0><<<g, 256, 0, stream>>>(f3, lin1, nullptr, fc1, 32, 512, 1024);
    }
    {
        dim3 g(ceil_div(256, 64), 1);
        gemm_kernel<1,0><<<g, 256, 0, stream>>>(fc1, lin2, nullptr, fc2, 32, 256, 512);
    }
    {
        dim3 g(1, 1);
        gemm_kernel<0,1><<<g, 256, 0, stream>>>(fc2, clsw, clsb, (float*)d_out, 32, 40, 256);
    }
}

// Round 4
// 2262.949 us; speedup vs baseline: 1.7029x; 1.0748x over previous
//
#include <hip/hip_runtime.h>

#define DEVFN __device__ __forceinline__

static inline int ceil_div(int a, int b) { return (a + b - 1) / b; }

// ---------------------------------------------------------------------------
// Farthest point sampling — SINGLE WAVE per batch (unchanged from R3).
// ---------------------------------------------------------------------------
template<int N>
__global__ __launch_bounds__(64) void fps_kernel(const float* __restrict__ xyz, int M,
                                                 int* __restrict__ out_idx,
                                                 float* __restrict__ nxout)
{
    constexpr int PPL = N / 64;
    int b = blockIdx.x, lane = threadIdx.x;
    __shared__ float sx[N], sy[N], sz[N];
    const float* p = xyz + (size_t)b * N * 3;
    float px[PPL], py[PPL], pz[PPL], dd[PPL];
    #pragma unroll
    for (int j = 0; j < PPL; ++j) {
        int idx = lane + 64 * j;
        px[j] = p[idx*3+0]; py[j] = p[idx*3+1]; pz[j] = p[idx*3+2];
        sx[idx] = px[j]; sy[idx] = py[j]; sz[idx] = pz[j];
        dd[j] = 1e10f;
    }
    __syncthreads();
    int far = 0;
    for (int s = 0; s < M; ++s) {
        float cx = sx[far], cy = sy[far], cz = sz[far];
        if (lane == 0) {
            out_idx[(size_t)b*M + s] = far;
            nxout[((size_t)b*M + s)*3 + 0] = cx;
            nxout[((size_t)b*M + s)*3 + 1] = cy;
            nxout[((size_t)b*M + s)*3 + 2] = cz;
        }
        float best = -1.0f; int bi = 0;
        #pragma unroll
        for (int j = 0; j < PPL; ++j) {
            float dx = __fsub_rn(px[j], cx);
            float dy = __fsub_rn(py[j], cy);
            float dz = __fsub_rn(pz[j], cz);
            float d  = __fadd_rn(__fadd_rn(__fmul_rn(dx,dx), __fmul_rn(dy,dy)),
                                 __fmul_rn(dz,dz));
            float nd = fminf(dd[j], d);
            dd[j] = nd;
            if (nd > best) { best = nd; bi = lane + 64*j; }  // strict >: first occurrence
        }
        #pragma unroll
        for (int o = 32; o > 0; o >>= 1) {
            float v2 = __shfl_xor(best, o);
            int   i2 = __shfl_xor(bi, o);
            if (v2 > best || (v2 == best && i2 < bi)) { best = v2; bi = i2; }
        }
        far = bi;   // uniform across the wave
    }
}

// ---------------------------------------------------------------------------
// Ball query (unchanged).
// ---------------------------------------------------------------------------
__global__ void ballquery_kernel(const float* __restrict__ xyz,
                                 const float* __restrict__ new_xyz,
                                 int* __restrict__ gi,
                                 int B, int N, int M, int K, float r2)
{
    int t = blockIdx.x * blockDim.x + threadIdx.x;
    if (t >= B * M) return;
    int b = t / M;
    const float* p = xyz + (size_t)b * N * 3;
    float cx = new_xyz[t*3+0], cy = new_xyz[t*3+1], cz = new_xyz[t*3+2];
    int* out = gi + (size_t)t * K;
    int cnt = 0, first = 0;
    bool havefirst = false;
    for (int i = 0; i < N; ++i) {
        float dx = __fsub_rn(p[i*3+0], cx);
        float dy = __fsub_rn(p[i*3+1], cy);
        float dz = __fsub_rn(p[i*3+2], cz);
        float d  = __fadd_rn(__fadd_rn(__fmul_rn(dx,dx), __fmul_rn(dy,dy)),
                             __fmul_rn(dz,dz));
        if (d <= r2) {
            if (!havefirst) { first = i; havefirst = true; }
            out[cnt++] = i;
            if (cnt == K) break;
        }
    }
    for (; cnt < K; ++cnt) out[cnt] = first;
}

// ---------------------------------------------------------------------------
// SA MLP layer, wave-uniform weights. lane = row (+64 per extra RPL row).
// Each wave owns a CO/4 column slice -> weight & bias reads are s_loads
// (SGPR broadcast), inner loop = RPL ds_read + RPL*WCH v_fmac per ci.
// LDS strides odd => 2-way bank aliasing (free).
// ---------------------------------------------------------------------------
template<int CI, int IS, int CO, int OS, int RPL>
DEVFN void layerW(const float* __restrict__ in, const float* __restrict__ w,
                  const float* __restrict__ bias, float* __restrict__ out,
                  int wv, int lane)
{
    constexpr int WCH = CO / 4;
    const float* wcol = w + wv * WCH;          // wave-uniform
    float acc[RPL][WCH];
    #pragma unroll
    for (int j = 0; j < WCH; ++j) {
        float bv = bias[wv*WCH + j];           // s_load
        #pragma unroll
        for (int i = 0; i < RPL; ++i) acc[i][j] = bv;
    }
    #pragma unroll 2
    for (int ci = 0; ci < CI; ++ci) {
        float av[RPL];
        #pragma unroll
        for (int i = 0; i < RPL; ++i) av[i] = in[(lane + 64*i)*IS + ci];
        #pragma unroll
        for (int j = 0; j < WCH; ++j) {
            float wj = wcol[(size_t)ci*CO + j];   // s_load (uniform addr)
            #pragma unroll
            for (int i = 0; i < RPL; ++i) acc[i][j] += av[i] * wj;
        }
    }
    #pragma unroll
    for (int i = 0; i < RPL; ++i)
        #pragma unroll
        for (int j = 0; j < WCH; ++j)
            out[(lane + 64*i)*OS + wv*WCH + j] = fmaxf(acc[i][j], 0.f);
}

// Final layer: relu then max over each KPTS-lane group via shfl butterfly,
// group-leader lanes store their centroid's CO/4 slice.
template<int CI, int IS, int CO, int KPTS, int RPL>
DEVFN void layerW_max(const float* __restrict__ in, const float* __restrict__ w,
                      const float* __restrict__ bias, float* __restrict__ fout_base,
                      int wv, int lane)
{
    constexpr int WCH = CO / 4;
    const float* wcol = w + wv * WCH;
    float acc[RPL][WCH];
    #pragma unroll
    for (int j = 0; j < WCH; ++j) {
        float bv = bias[wv*WCH + j];
        #pragma unroll
        for (int i = 0; i < RPL; ++i) acc[i][j] = bv;
    }
    #pragma unroll 2
    for (int ci = 0; ci < CI; ++ci) {
        float av[RPL];
        #pragma unroll
        for (int i = 0; i < RPL; ++i) av[i] = in[(lane + 64*i)*IS + ci];
        #pragma unroll
        for (int j = 0; j < WCH; ++j) {
            float wj = wcol[(size_t)ci*CO + j];
            #pragma unroll
            for (int i = 0; i < RPL; ++i) acc[i][j] += av[i] * wj;
        }
    }
    #pragma unroll
    for (int i = 0; i < RPL; ++i) {
        #pragma unroll
        for (int j = 0; j < WCH; ++j) acc[i][j] = fmaxf(acc[i][j], 0.f);
        #pragma unroll
        for (int off = KPTS/2; off > 0; off >>= 1)
            #pragma unroll
            for (int j = 0; j < WCH; ++j)
                acc[i][j] = fmaxf(acc[i][j], __shfl_xor(acc[i][j], off));
    }
    if ((lane & (KPTS-1)) == 0) {
        #pragma unroll
        for (int i = 0; i < RPL; ++i) {
            int cent = (lane + 64*i) / KPTS;
            #pragma unroll
            for (int j = 0; j < WCH; ++j)
                fout_base[(size_t)cent*CO + wv*WCH + j] = acc[i][j];
        }
    }
}

// ---------------------------------------------------------------------------
// Fused set-abstraction MLP. Block = 256 threads = 4 waves; CPB centroids of
// KPTS points; ROWS = CPB*KPTS = 64*RPL rows; lane owns rows lane+64i.
// Waves split CO 4-ways (uniform weights -> SGPR). 3 layers + fused max.
// ---------------------------------------------------------------------------
template<int KPTS, int CPB, int RPL, int CF, int C1, int C2, int C3>
__global__ __launch_bounds__(256) void sa_mlp_kernel(
    const float* __restrict__ xyz, const float* __restrict__ feats,
    const float* __restrict__ new_xyz, const int* __restrict__ gi,
    const float* __restrict__ w1, const float* __restrict__ b1,
    const float* __restrict__ w2, const float* __restrict__ b2,
    const float* __restrict__ w3, const float* __restrict__ b3,
    float* __restrict__ fout, int N, int M)
{
    constexpr int CIN  = CF + 3;
    constexpr int ROWS = 64 * RPL;
    static_assert(CPB * KPTS == ROWS, "rows");
    constexpr int SIN  = (CIN % 2 == 0) ? CIN + 1 : CIN;   // odd stride
    constexpr int S1   = C1 + 1;
    constexpr bool ALIAS = (SIN >= C2 + 1);                // reuse bufIn for layer2 out
    constexpr int S2   = ALIAS ? SIN : (C2 + 1);
    __shared__ float bufIn[ROWS * SIN];
    __shared__ float buf1[ROWS * S1];
    __shared__ float buf2sep[ALIAS ? 1 : ROWS * (C2 + 1)];
    __shared__ int   sgi[ROWS];
    float* buf2 = ALIAS ? bufIn : buf2sep;

    const int bm   = blockIdx.x;
    const int b    = (bm * CPB) / M;
    const int lane = threadIdx.x & 63;
    const int wv   = __builtin_amdgcn_readfirstlane(threadIdx.x >> 6);

    if (threadIdx.x < ROWS) sgi[threadIdx.x] = gi[(size_t)bm * ROWS + threadIdx.x];
    __syncthreads();

    for (int e = threadIdx.x; e < ROWS * CIN; e += 256) {
        int row = e / CIN, c = e % CIN;
        int idx = sgi[row];
        int cent = row / KPTS;
        float v;
        if (c < 3) v = __fsub_rn(xyz[((size_t)b*N + idx)*3 + c],
                                 new_xyz[((size_t)bm*CPB + cent)*3 + c]);
        else       v = feats[((size_t)b*N + idx)*CF + (c - 3)];
        bufIn[row*SIN + c] = v;
    }
    __syncthreads();
    layerW<CIN, SIN, C1, S1, RPL>(bufIn, w1, b1, buf1, wv, lane);
    __syncthreads();
    layerW<C1, S1, C2, S2, RPL>(buf1, w2, b2, buf2, wv, lane);
    __syncthreads();
    layerW_max<C2, S2, C3, KPTS, RPL>(buf2, w3, b3,
                                      fout + (size_t)bm * CPB * C3, wv, lane);
}

// ---------------------------------------------------------------------------
// concat [R,3] ++ [R,CF] -> [R,3+CF]
// ---------------------------------------------------------------------------
__global__ void concat_kernel(const float* __restrict__ a, const float* __restrict__ f,
                              float* __restrict__ out, int R, int CF)
{
    int C = CF + 3;
    int t = blockIdx.x * blockDim.x + threadIdx.x;
    if (t >= R * C) return;
    int r = t / C, c = t % C;
    out[t] = (c < 3) ? a[r*3 + c] : f[(size_t)r * CF + (c - 3)];
}

// ---------------------------------------------------------------------------
// Tiled fp32 GEMM, 64x64 tile / 4x4 micro (small shapes + FC head).
// ---------------------------------------------------------------------------
template<int RELU, int HASB>
__global__ __launch_bounds__(256) void gemm_kernel(
    const float* __restrict__ A, const float* __restrict__ W,
    const float* __restrict__ bias, float* __restrict__ Cc,
    int Mr, int Nc, int Kd)
{
    __shared__ float As[64][17];
    __shared__ float Ws[16][65];
    int tx = threadIdx.x % 16;
    int ty = threadIdx.x / 16;
    int row0 = blockIdx.y * 64;
    int col0 = blockIdx.x * 64;
    float acc[4][4] = {};
    for (int k0 = 0; k0 < Kd; k0 += 16) {
        for (int t = threadIdx.x; t < 64*16; t += 256) {
            int r = t >> 4, kk = t & 15;
            int gr = row0 + r, gk = k0 + kk;
            As[r][kk] = (gr < Mr && gk < Kd) ? A[(size_t)gr * Kd + gk] : 0.f;
        }
        for (int t = threadIdx.x; t < 16*64; t += 256) {
            int kk = t >> 6, c = t & 63;
            int gk = k0 + kk, gc = col0 + c;
            Ws[kk][c] = (gk < Kd && gc < Nc) ? W[(size_t)gk * Nc + gc] : 0.f;
        }
        __syncthreads();
        #pragma unroll
        for (int kk = 0; kk < 16; ++kk) {
            float av[4], wv[4];
            #pragma unroll
            for (int i = 0; i < 4; i++) av[i] = As[ty*4+i][kk];
            #pragma unroll
            for (int j = 0; j < 4; j++) wv[j] = Ws[kk][tx*4+j];
            #pragma unroll
            for (int i = 0; i < 4; i++)
                #pragma unroll
                for (int j = 0; j < 4; j++)
                    acc[i][j] += av[i] * wv[j];
        }
        __syncthreads();
    }
    #pragma unroll
    for (int i = 0; i < 4; i++) {
        int gr = row0 + ty*4 + i;
        if (gr >= Mr) continue;
        #pragma unroll
        for (int j = 0; j < 4; j++) {
            int gc = col0 + tx*4 + j;
            if (gc >= Nc) continue;
            float v = acc[i][j];
            if (HASB) v += bias[gc];
            if (RELU) v = fmaxf(v, 0.f);
            Cc[(size_t)gr * Nc + gc] = v;
        }
    }
}

// ---------------------------------------------------------------------------
// Tiled fp32 GEMM, 128x128 tile / 8x8 micro (strided fragment mapping).
// ---------------------------------------------------------------------------
template<int RELU, int HASB>
__global__ __launch_bounds__(256, 2) void gemm128_kernel(
    const float* __restrict__ A, const float* __restrict__ W,
    const float* __restrict__ bias, float* __restrict__ Cc,
    int Mr, int Nc, int Kd)
{
    __shared__ float As[128][17];
    __shared__ float Ws[16][132];
    int tx = threadIdx.x % 16;
    int ty = threadIdx.x / 16;
    int row0 = blockIdx.y * 128;
    int col0 = blockIdx.x * 128;
    float acc[8][8] = {};
    for (int k0 = 0; k0 < Kd; k0 += 16) {
        for (int t = threadIdx.x; t < 128*16; t += 256) {
            int r = t >> 4, kk = t & 15;
            int gr = row0 + r, gk = k0 + kk;
            As[r][kk] = (gr < Mr && gk < Kd) ? A[(size_t)gr * Kd + gk] : 0.f;
        }
        for (int t = threadIdx.x; t < 16*128; t += 256) {
            int kk = t >> 7, c = t & 127;
            int gk = k0 + kk, gc = col0 + c;
            Ws[kk][c] = (gk < Kd && gc < Nc) ? W[(size_t)gk * Nc + gc] : 0.f;
        }
        __syncthreads();
        #pragma unroll
        for (int kk = 0; kk < 16; ++kk) {
            float av[8], wv[8];
            #pragma unroll
            for (int i = 0; i < 8; i++) av[i] = As[ty + 16*i][kk];
            #pragma unroll
            for (int j = 0; j < 8; j++) wv[j] = Ws[kk][tx + 16*j];
            #pragma unroll
            for (int i = 0; i < 8; i++)
                #pragma unroll
                for (int j = 0; j < 8; j++)
                    acc[i][j] += av[i] * wv[j];
        }
        __syncthreads();
    }
    #pragma unroll
    for (int i = 0; i < 8; i++) {
        int gr = row0 + ty + 16*i;
        if (gr >= Mr) continue;
        #pragma unroll
        for (int j = 0; j < 8; j++) {
            int gc = col0 + tx + 16*j;
            if (gc >= Nc) continue;
            float v = acc[i][j];
            if (HASB) v += bias[gc];
            if (RELU) v = fmaxf(v, 0.f);
            Cc[(size_t)gr * Nc + gc] = v;
        }
    }
}

// ---------------------------------------------------------------------------
// Max over P points: in [B,P,C] -> out [B,C]
// ---------------------------------------------------------------------------
__global__ void rowmax_kernel(const float* __restrict__ in, float* __restrict__ out,
                              int B, int P, int C)
{
    int t = blockIdx.x * blockDim.x + threadIdx.x;
    if (t >= B * C) return;
    int b = t / C, c = t % C;
    const float* p = in + (size_t)b * P * C + c;
    float mx = p[0];
    for (int i = 1; i < P; ++i) mx = fmaxf(mx, p[(size_t)i * C]);
    out[t] = mx;
}

// ---------------------------------------------------------------------------
extern "C" void kernel_launch(void* const* d_in, const int* in_sizes, int n_in,
                              void* d_out, int out_size, void* d_ws, size_t ws_size,
                              hipStream_t stream)
{
    const float* xyz    = (const float*)d_in[0];
    const float* points = (const float*)d_in[1];
    const float* w1a = (const float*)d_in[2];  const float* b1a = (const float*)d_in[3];
    const float* w1b = (const float*)d_in[4];  const float* b1b = (const float*)d_in[5];
    const float* w1c = (const float*)d_in[6];  const float* b1c = (const float*)d_in[7];
    const float* w2a = (const float*)d_in[8];  const float* b2a = (const float*)d_in[9];
    const float* w2b = (const float*)d_in[10]; const float* b2b = (const float*)d_in[11];
    const float* w2c = (const float*)d_in[12]; const float* b2c = (const float*)d_in[13];
    const float* w3a = (const float*)d_in[14]; const float* b3a = (const float*)d_in[15];
    const float* w3b = (const float*)d_in[16]; const float* b3b = (const float*)d_in[17];
    const float* w3c = (const float*)d_in[18]; const float* b3c = (const float*)d_in[19];
    const float* lin1 = (const float*)d_in[20];
    const float* lin2 = (const float*)d_in[21];
    const float* clsw = (const float*)d_in[22];
    const float* clsb = (const float*)d_in[23];

    char* ws = (char*)d_ws;
    size_t off = 0;
    auto alloc = [&](size_t bytes) -> void* {
        void* p = ws + off;
        off += (bytes + 255) & ~(size_t)255;
        return p;
    };
    int*   fps1 = (int*)  alloc((size_t)32*512*4);
    float* nx1  = (float*)alloc((size_t)32*512*3*4);
    int*   gi1  = (int*)  alloc((size_t)32*512*32*4);
    float* f1   = (float*)alloc((size_t)32*512*128*4);
    int*   fps2 = (int*)  alloc((size_t)32*128*4);
    float* nx2  = (float*)alloc((size_t)32*128*3*4);
    int*   gi2  = (int*)  alloc((size_t)32*128*64*4);
    float* f2   = (float*)alloc((size_t)32*128*256*4);
    float* g3   = (float*)alloc((size_t)4096*259*4);
    float* h3a  = (float*)alloc((size_t)4096*256*4);
    float* h3b  = (float*)alloc((size_t)4096*512*4);
    float* h3c  = (float*)alloc((size_t)4096*1024*4);
    float* f3   = (float*)alloc((size_t)32*1024*4);
    float* fc1  = (float*)alloc((size_t)32*512*4);
    float* fc2  = (float*)alloc((size_t)32*256*4);

    // ---- SA1: N=1024 -> M=512, r=0.2, K=32, MLP 6->64->64->128
    fps_kernel<1024><<<32, 64, 0, stream>>>(xyz, 512, fps1, nx1);
    ballquery_kernel<<<ceil_div(32*512, 256), 256, 0, stream>>>(
        xyz, nx1, gi1, 32, 1024, 512, 32, (float)(0.2*0.2));
    // 2 centroids/block, 64 rows, 1 row/lane
    sa_mlp_kernel<32, 2, 1, 3, 64, 64, 128><<<32*512/2, 256, 0, stream>>>(
        xyz, points, nx1, gi1, w1a, b1a, w1b, b1b, w1c, b1c, f1, 1024, 512);

    // ---- SA2: N=512 -> M=128, r=0.4, K=64, MLP 131->128->128->256
    fps_kernel<512><<<32, 64, 0, stream>>>(nx1, 128, fps2, nx2);
    ballquery_kernel<<<ceil_div(32*128, 256), 256, 0, stream>>>(
        nx1, nx2, gi2, 32, 512, 128, 64, (float)(0.4*0.4));
    // 1 centroid/block, 64 rows, 1 row/lane
    sa_mlp_kernel<64, 1, 1, 128, 128, 128, 256><<<32*128, 256, 0, stream>>>(
        nx1, f1, nx2, gi2, w2a, b2a, w2b, b2b, w2c, b2c, f2, 512, 128);

    // ---- SA3 (group_all): concat [4096, 259] -> MLP 259->256->512->1024 -> max over 128
    concat_kernel<<<ceil_div(4096*259, 256), 256, 0, stream>>>(nx2, f2, g3, 4096, 256);
    {
        dim3 g(ceil_div(256, 64), ceil_div(4096, 64));
        gemm_kernel<1,1><<<g, 256, 0, stream>>>(g3, w3a, b3a, h3a, 4096, 256, 259);
    }
    {
        dim3 g(ceil_div(512, 128), ceil_div(4096, 128));
        gemm128_kernel<1,1><<<g, 256, 0, stream>>>(h3a, w3b, b3b, h3b, 4096, 512, 256);
    }
    {
        dim3 g(ceil_div(1024, 128), ceil_div(4096, 128));
        gemm128_kernel<1,1><<<g, 256, 0, stream>>>(h3b, w3c, b3c, h3c, 4096, 1024, 512);
    }
    rowmax_kernel<<<ceil_div(32*1024, 256), 256, 0, stream>>>(h3c, f3, 32, 128, 1024);

    // ---- FC head
    {
        dim3 g(ceil_div(512, 64), 1);
        gemm_kernel<1,0><<<g, 256, 0, stream>>>(f3, lin1, nullptr, fc1, 32, 512, 1024);
    }
    {
        dim3 g(ceil_div(256, 64), 1);
        gemm_kernel<1,0><<<g, 256, 0, stream>>>(fc1, lin2, nullptr, fc2, 32, 256, 512);
    }
    {
        dim3 g(1, 1);
        gemm_kernel<0,1><<<g, 256, 0, stream>>>(fc2, clsw, clsb, (float*)d_out, 32, 40, 256);
    }
}

// Round 5
// 2228.853 us; speedup vs baseline: 1.7289x; 1.0153x over previous
//
#include <hip/hip_runtime.h>

#define DEVFN __device__ __forceinline__

static inline int ceil_div(int a, int b) { return (a + b - 1) / b; }

// Pad C up to a multiple of 4 whose quad-count (S/4) is odd -> b128 reads by
// 64 row-lanes spread across all 8 bank-quads (<=8-way, hidden under FMAs).
constexpr int pad4(int c) { int s = (c + 3) & ~3; return ((s >> 2) & 1) ? s : s + 4; }

// ---------------------------------------------------------------------------
// Farthest point sampling — SINGLE WAVE per batch (unchanged).
// ---------------------------------------------------------------------------
template<int N>
__global__ __launch_bounds__(64) void fps_kernel(const float* __restrict__ xyz, int M,
                                                 int* __restrict__ out_idx,
                                                 float* __restrict__ nxout)
{
    constexpr int PPL = N / 64;
    int b = blockIdx.x, lane = threadIdx.x;
    __shared__ float sx[N], sy[N], sz[N];
    const float* p = xyz + (size_t)b * N * 3;
    float px[PPL], py[PPL], pz[PPL], dd[PPL];
    #pragma unroll
    for (int j = 0; j < PPL; ++j) {
        int idx = lane + 64 * j;
        px[j] = p[idx*3+0]; py[j] = p[idx*3+1]; pz[j] = p[idx*3+2];
        sx[idx] = px[j]; sy[idx] = py[j]; sz[idx] = pz[j];
        dd[j] = 1e10f;
    }
    __syncthreads();
    int far = 0;
    for (int s = 0; s < M; ++s) {
        float cx = sx[far], cy = sy[far], cz = sz[far];
        if (lane == 0) {
            out_idx[(size_t)b*M + s] = far;
            nxout[((size_t)b*M + s)*3 + 0] = cx;
            nxout[((size_t)b*M + s)*3 + 1] = cy;
            nxout[((size_t)b*M + s)*3 + 2] = cz;
        }
        float best = -1.0f; int bi = 0;
        #pragma unroll
        for (int j = 0; j < PPL; ++j) {
            float dx = __fsub_rn(px[j], cx);
            float dy = __fsub_rn(py[j], cy);
            float dz = __fsub_rn(pz[j], cz);
            float d  = __fadd_rn(__fadd_rn(__fmul_rn(dx,dx), __fmul_rn(dy,dy)),
                                 __fmul_rn(dz,dz));
            float nd = fminf(dd[j], d);
            dd[j] = nd;
            if (nd > best) { best = nd; bi = lane + 64*j; }  // strict >: first occurrence
        }
        #pragma unroll
        for (int o = 32; o > 0; o >>= 1) {
            float v2 = __shfl_xor(best, o);
            int   i2 = __shfl_xor(bi, o);
            if (v2 > best || (v2 == best && i2 < bi)) { best = v2; bi = i2; }
        }
        far = bi;   // uniform across the wave
    }
}

// ---------------------------------------------------------------------------
// Ball query (unchanged).
// ---------------------------------------------------------------------------
__global__ void ballquery_kernel(const float* __restrict__ xyz,
                                 const float* __restrict__ new_xyz,
                                 int* __restrict__ gi,
                                 int B, int N, int M, int K, float r2)
{
    int t = blockIdx.x * blockDim.x + threadIdx.x;
    if (t >= B * M) return;
    int b = t / M;
    const float* p = xyz + (size_t)b * N * 3;
    float cx = new_xyz[t*3+0], cy = new_xyz[t*3+1], cz = new_xyz[t*3+2];
    int* out = gi + (size_t)t * K;
    int cnt = 0, first = 0;
    bool havefirst = false;
    for (int i = 0; i < N; ++i) {
        float dx = __fsub_rn(p[i*3+0], cx);
        float dy = __fsub_rn(p[i*3+1], cy);
        float dz = __fsub_rn(p[i*3+2], cz);
        float d  = __fadd_rn(__fadd_rn(__fmul_rn(dx,dx), __fmul_rn(dy,dy)),
                             __fmul_rn(dz,dz));
        if (d <= r2) {
            if (!havefirst) { first = i; havefirst = true; }
            out[cnt++] = i;
            if (cnt == K) break;
        }
    }
    for (; cnt < K; ++cnt) out[cnt] = first;
}

DEVFN float f4_elem(const float4& v, int u) {  // u is compile-time after unroll
    return u == 0 ? v.x : u == 1 ? v.y : u == 2 ? v.z : v.w;
}

// ---------------------------------------------------------------------------
// SA MLP layer, wave-uniform weights (SGPR broadcast). lane = row (+64*i).
// Activations read as ds_read_b128 (4 ci per wait) to amortize the
// SMEM/LDS mixed-lgkmcnt drain; fp add order over ci unchanged.
// ---------------------------------------------------------------------------
template<int CI, int IS, int CO, int OS, int RPL>
DEVFN void layerW(const float* __restrict__ in, const float* __restrict__ w,
                  const float* __restrict__ bias, float* __restrict__ out,
                  int wv, int lane)
{
    constexpr int WCH = CO / 4;
    constexpr int CI4 = CI & ~3;
    const float* wcol = w + wv * WCH;          // wave-uniform
    float acc[RPL][WCH];
    #pragma unroll
    for (int j = 0; j < WCH; ++j) {
        float bv = bias[wv*WCH + j];           // s_load
        #pragma unroll
        for (int i = 0; i < RPL; ++i) acc[i][j] = bv;
    }
    for (int cc = 0; cc < CI4; cc += 4) {
        float4 av4[RPL];
        #pragma unroll
        for (int i = 0; i < RPL; ++i)
            av4[i] = *(const float4*)&in[(lane + 64*i)*IS + cc];
        #pragma unroll
        for (int u = 0; u < 4; ++u) {
            #pragma unroll
            for (int j = 0; j < WCH; ++j) {
                float wj = wcol[(size_t)(cc + u)*CO + j];   // s_load (uniform)
                #pragma unroll
                for (int i = 0; i < RPL; ++i) acc[i][j] += f4_elem(av4[i], u) * wj;
            }
        }
    }
    #pragma unroll
    for (int ci = CI4; ci < CI; ++ci) {
        float av[RPL];
        #pragma unroll
        for (int i = 0; i < RPL; ++i) av[i] = in[(lane + 64*i)*IS + ci];
        #pragma unroll
        for (int j = 0; j < WCH; ++j) {
            float wj = wcol[(size_t)ci*CO + j];
            #pragma unroll
            for (int i = 0; i < RPL; ++i) acc[i][j] += av[i] * wj;
        }
    }
    #pragma unroll
    for (int i = 0; i < RPL; ++i) {
        float* op = out + (lane + 64*i)*OS + wv*WCH;
        #pragma unroll
        for (int j4 = 0; j4 < WCH; j4 += 4) {
            float4 v;
            v.x = fmaxf(acc[i][j4+0], 0.f);
            v.y = fmaxf(acc[i][j4+1], 0.f);
            v.z = fmaxf(acc[i][j4+2], 0.f);
            v.w = fmaxf(acc[i][j4+3], 0.f);
            *(float4*)(op + j4) = v;
        }
    }
}

// Final layer: relu then max over each KPTS-lane group via shfl butterfly,
// group-leader lanes store their centroid's CO/4 slice (float4 stores).
template<int CI, int IS, int CO, int KPTS, int RPL>
DEVFN void layerW_max(const float* __restrict__ in, const float* __restrict__ w,
                      const float* __restrict__ bias, float* __restrict__ fout_base,
                      int wv, int lane)
{
    constexpr int WCH = CO / 4;
    constexpr int CI4 = CI & ~3;
    const float* wcol = w + wv * WCH;
    float acc[RPL][WCH];
    #pragma unroll
    for (int j = 0; j < WCH; ++j) {
        float bv = bias[wv*WCH + j];
        #pragma unroll
        for (int i = 0; i < RPL; ++i) acc[i][j] = bv;
    }
    for (int cc = 0; cc < CI4; cc += 4) {
        float4 av4[RPL];
        #pragma unroll
        for (int i = 0; i < RPL; ++i)
            av4[i] = *(const float4*)&in[(lane + 64*i)*IS + cc];
        #pragma unroll
        for (int u = 0; u < 4; ++u) {
            #pragma unroll
            for (int j = 0; j < WCH; ++j) {
                float wj = wcol[(size_t)(cc + u)*CO + j];
                #pragma unroll
                for (int i = 0; i < RPL; ++i) acc[i][j] += f4_elem(av4[i], u) * wj;
            }
        }
    }
    #pragma unroll
    for (int ci = CI4; ci < CI; ++ci) {
        float av[RPL];
        #pragma unroll
        for (int i = 0; i < RPL; ++i) av[i] = in[(lane + 64*i)*IS + ci];
        #pragma unroll
        for (int j = 0; j < WCH; ++j) {
            float wj = wcol[(size_t)ci*CO + j];
            #pragma unroll
            for (int i = 0; i < RPL; ++i) acc[i][j] += av[i] * wj;
        }
    }
    #pragma unroll
    for (int i = 0; i < RPL; ++i) {
        #pragma unroll
        for (int j = 0; j < WCH; ++j) acc[i][j] = fmaxf(acc[i][j], 0.f);
        #pragma unroll
        for (int off = KPTS/2; off > 0; off >>= 1)
            #pragma unroll
            for (int j = 0; j < WCH; ++j)
                acc[i][j] = fmaxf(acc[i][j], __shfl_xor(acc[i][j], off));
    }
    if ((lane & (KPTS-1)) == 0) {
        #pragma unroll
        for (int i = 0; i < RPL; ++i) {
            int cent = (lane + 64*i) / KPTS;
            float* op = fout_base + (size_t)cent*CO + wv*WCH;
            #pragma unroll
            for (int j4 = 0; j4 < WCH; j4 += 4) {
                float4 v;
                v.x = acc[i][j4+0]; v.y = acc[i][j4+1];
                v.z = acc[i][j4+2]; v.w = acc[i][j4+3];
                *(float4*)(op + j4) = v;
            }
        }
    }
}

// ---------------------------------------------------------------------------
// Fused set-abstraction MLP. Block = 256 threads = 4 waves; CPB centroids of
// KPTS points; ROWS = CPB*KPTS = 64*RPL rows; lane owns rows lane+64i.
// Waves split CO 4-ways (uniform weights -> SGPR). 3 layers + fused max.
// ---------------------------------------------------------------------------
template<int KPTS, int CPB, int RPL, int CF, int C1, int C2, int C3>
__global__ __launch_bounds__(256) void sa_mlp_kernel(
    const float* __restrict__ xyz, const float* __restrict__ feats,
    const float* __restrict__ new_xyz, const int* __restrict__ gi,
    const float* __restrict__ w1, const float* __restrict__ b1,
    const float* __restrict__ w2, const float* __restrict__ b2,
    const float* __restrict__ w3, const float* __restrict__ b3,
    float* __restrict__ fout, int N, int M)
{
    constexpr int CIN  = CF + 3;
    constexpr int ROWS = 64 * RPL;
    static_assert(CPB * KPTS == ROWS, "rows");
    constexpr int SIN  = pad4(CIN);
    constexpr int S1   = pad4(C1);
    constexpr int S2c  = pad4(C2);
    constexpr bool ALIAS = (SIN >= S2c);               // reuse bufIn for layer2 out
    constexpr int S2   = ALIAS ? SIN : S2c;
    __shared__ float bufIn[ROWS * SIN];
    __shared__ float buf1[ROWS * S1];
    __shared__ float buf2sep[ALIAS ? 1 : ROWS * S2c];
    __shared__ int   sgi[ROWS];
    float* buf2 = ALIAS ? bufIn : buf2sep;

    const int bm   = blockIdx.x;
    const int b    = (bm * CPB) / M;
    const int lane = threadIdx.x & 63;
    const int wv   = __builtin_amdgcn_readfirstlane(threadIdx.x >> 6);

    if (threadIdx.x < ROWS) sgi[threadIdx.x] = gi[(size_t)bm * ROWS + threadIdx.x];
    __syncthreads();

    for (int e = threadIdx.x; e < ROWS * CIN; e += 256) {
        int row = e / CIN, c = e % CIN;
        int idx = sgi[row];
        int cent = row / KPTS;
        float v;
        if (c < 3) v = __fsub_rn(xyz[((size_t)b*N + idx)*3 + c],
                                 new_xyz[((size_t)bm*CPB + cent)*3 + c]);
        else       v = feats[((size_t)b*N + idx)*CF + (c - 3)];
        bufIn[row*SIN + c] = v;
    }
    __syncthreads();
    layerW<CIN, SIN, C1, S1, RPL>(bufIn, w1, b1, buf1, wv, lane);
    __syncthreads();
    layerW<C1, S1, C2, S2, RPL>(buf1, w2, b2, buf2, wv, lane);
    __syncthreads();
    layerW_max<C2, S2, C3, KPTS, RPL>(buf2, w3, b3,
                                      fout + (size_t)bm * CPB * C3, wv, lane);
}

// ---------------------------------------------------------------------------
// concat [R,3] ++ [R,CF] -> [R,3+CF]
// ---------------------------------------------------------------------------
__global__ void concat_kernel(const float* __restrict__ a, const float* __restrict__ f,
                              float* __restrict__ out, int R, int CF)
{
    int C = CF + 3;
    int t = blockIdx.x * blockDim.x + threadIdx.x;
    if (t >= R * C) return;
    int r = t / C, c = t % C;
    out[t] = (c < 3) ? a[r*3 + c] : f[(size_t)r * CF + (c - 3)];
}

// ---------------------------------------------------------------------------
// Tiled fp32 GEMM, 64x64 tile / 4x4 micro (small shapes + FC head).
// ---------------------------------------------------------------------------
template<int RELU, int HASB>
__global__ __launch_bounds__(256) void gemm_kernel(
    const float* __restrict__ A, const float* __restrict__ W,
    const float* __restrict__ bias, float* __restrict__ Cc,
    int Mr, int Nc, int Kd)
{
    __shared__ float As[64][17];
    __shared__ float Ws[16][65];
    int tx = threadIdx.x % 16;
    int ty = threadIdx.x / 16;
    int row0 = blockIdx.y * 64;
    int col0 = blockIdx.x * 64;
    float acc[4][4] = {};
    for (int k0 = 0; k0 < Kd; k0 += 16) {
        for (int t = threadIdx.x; t < 64*16; t += 256) {
            int r = t >> 4, kk = t & 15;
            int gr = row0 + r, gk = k0 + kk;
            As[r][kk] = (gr < Mr && gk < Kd) ? A[(size_t)gr * Kd + gk] : 0.f;
        }
        for (int t = threadIdx.x; t < 16*64; t += 256) {
            int kk = t >> 6, c = t & 63;
            int gk = k0 + kk, gc = col0 + c;
            Ws[kk][c] = (gk < Kd && gc < Nc) ? W[(size_t)gk * Nc + gc] : 0.f;
        }
        __syncthreads();
        #pragma unroll
        for (int kk = 0; kk < 16; ++kk) {
            float av[4], wv[4];
            #pragma unroll
            for (int i = 0; i < 4; i++) av[i] = As[ty*4+i][kk];
            #pragma unroll
            for (int j = 0; j < 4; j++) wv[j] = Ws[kk][tx*4+j];
            #pragma unroll
            for (int i = 0; i < 4; i++)
                #pragma unroll
                for (int j = 0; j < 4; j++)
                    acc[i][j] += av[i] * wv[j];
        }
        __syncthreads();
    }
    #pragma unroll
    for (int i = 0; i < 4; i++) {
        int gr = row0 + ty*4 + i;
        if (gr >= Mr) continue;
        #pragma unroll
        for (int j = 0; j < 4; j++) {
            int gc = col0 + tx*4 + j;
            if (gc >= Nc) continue;
            float v = acc[i][j];
            if (HASB) v += bias[gc];
            if (RELU) v = fmaxf(v, 0.f);
            Cc[(size_t)gr * Nc + gc] = v;
        }
    }
}

// ---------------------------------------------------------------------------
// Tiled fp32 GEMM, 128x128 tile / 8x8 micro (strided fragment mapping).
// ---------------------------------------------------------------------------
template<int RELU, int HASB>
__global__ __launch_bounds__(256, 2) void gemm128_kernel(
    const float* __restrict__ A, const float* __restrict__ W,
    const float* __restrict__ bias, float* __restrict__ Cc,
    int Mr, int Nc, int Kd)
{
    __shared__ float As[128][17];
    __shared__ float Ws[16][132];
    int tx = threadIdx.x % 16;
    int ty = threadIdx.x / 16;
    int row0 = blockIdx.y * 128;
    int col0 = blockIdx.x * 128;
    float acc[8][8] = {};
    for (int k0 = 0; k0 < Kd; k0 += 16) {
        for (int t = threadIdx.x; t < 128*16; t += 256) {
            int r = t >> 4, kk = t & 15;
            int gr = row0 + r, gk = k0 + kk;
            As[r][kk] = (gr < Mr && gk < Kd) ? A[(size_t)gr * Kd + gk] : 0.f;
        }
        for (int t = threadIdx.x; t < 16*128; t += 256) {
            int kk = t >> 7, c = t & 127;
            int gk = k0 + kk, gc = col0 + c;
            Ws[kk][c] = (gk < Kd && gc < Nc) ? W[(size_t)gk * Nc + gc] : 0.f;
        }
        __syncthreads();
        #pragma unroll
        for (int kk = 0; kk < 16; ++kk) {
            float av[8], wv[8];
            #pragma unroll
            for (int i = 0; i < 8; i++) av[i] = As[ty + 16*i][kk];
            #pragma unroll
            for (int j = 0; j < 8; j++) wv[j] = Ws[kk][tx + 16*j];
            #pragma unroll
            for (int i = 0; i < 8; i++)
                #pragma unroll
                for (int j = 0; j < 8; j++)
                    acc[i][j] += av[i] * wv[j];
        }
        __syncthreads();
    }
    #pragma unroll
    for (int i = 0; i < 8; i++) {
        int gr = row0 + ty + 16*i;
        if (gr >= Mr) continue;
        #pragma unroll
        for (int j = 0; j < 8; j++) {
            int gc = col0 + tx + 16*j;
            if (gc >= Nc) continue;
            float v = acc[i][j];
            if (HASB) v += bias[gc];
            if (RELU) v = fmaxf(v, 0.f);
            Cc[(size_t)gr * Nc + gc] = v;
        }
    }
}

// ---------------------------------------------------------------------------
// Max over P points: in [B,P,C] -> out [B,C]
// ---------------------------------------------------------------------------
__global__ void rowmax_kernel(const float* __restrict__ in, float* __restrict__ out,
                              int B, int P, int C)
{
    int t = blockIdx.x * blockDim.x + threadIdx.x;
    if (t >= B * C) return;
    int b = t / C, c = t % C;
    const float* p = in + (size_t)b * P * C + c;
    float mx = p[0];
    for (int i = 1; i < P; ++i) mx = fmaxf(mx, p[(size_t)i * C]);
    out[t] = mx;
}

// ---------------------------------------------------------------------------
extern "C" void kernel_launch(void* const* d_in, const int* in_sizes, int n_in,
                              void* d_out, int out_size, void* d_ws, size_t ws_size,
                              hipStream_t stream)
{
    const float* xyz    = (const float*)d_in[0];
    const float* points = (const float*)d_in[1];
    const float* w1a = (const float*)d_in[2];  const float* b1a = (const float*)d_in[3];
    const float* w1b = (const float*)d_in[4];  const float* b1b = (const float*)d_in[5];
    const float* w1c = (const float*)d_in[6];  const float* b1c = (const float*)d_in[7];
    const float* w2a = (const float*)d_in[8];  const float* b2a = (const float*)d_in[9];
    const float* w2b = (const float*)d_in[10]; const float* b2b = (const float*)d_in[11];
    const float* w2c = (const float*)d_in[12]; const float* b2c = (const float*)d_in[13];
    const float* w3a = (const float*)d_in[14]; const float* b3a = (const float*)d_in[15];
    const float* w3b = (const float*)d_in[16]; const float* b3b = (const float*)d_in[17];
    const float* w3c = (const float*)d_in[18]; const float* b3c = (const float*)d_in[19];
    const float* lin1 = (const float*)d_in[20];
    const float* lin2 = (const float*)d_in[21];
    const float* clsw = (const float*)d_in[22];
    const float* clsb = (const float*)d_in[23];

    char* ws = (char*)d_ws;
    size_t off = 0;
    auto alloc = [&](size_t bytes) -> void* {
        void* p = ws + off;
        off += (bytes + 255) & ~(size_t)255;
        return p;
    };
    int*   fps1 = (int*)  alloc((size_t)32*512*4);
    float* nx1  = (float*)alloc((size_t)32*512*3*4);
    int*   gi1  = (int*)  alloc((size_t)32*512*32*4);
    float* f1   = (float*)alloc((size_t)32*512*128*4);
    int*   fps2 = (int*)  alloc((size_t)32*128*4);
    float* nx2  = (float*)alloc((size_t)32*128*3*4);
    int*   gi2  = (int*)  alloc((size_t)32*128*64*4);
    float* f2   = (float*)alloc((size_t)32*128*256*4);
    float* g3   = (float*)alloc((size_t)4096*259*4);
    float* h3a  = (float*)alloc((size_t)4096*256*4);
    float* h3b  = (float*)alloc((size_t)4096*512*4);
    float* h3c  = (float*)alloc((size_t)4096*1024*4);
    float* f3   = (float*)alloc((size_t)32*1024*4);
    float* fc1  = (float*)alloc((size_t)32*512*4);
    float* fc2  = (float*)alloc((size_t)32*256*4);

    // ---- SA1: N=1024 -> M=512, r=0.2, K=32, MLP 6->64->64->128
    fps_kernel<1024><<<32, 64, 0, stream>>>(xyz, 512, fps1, nx1);
    ballquery_kernel<<<ceil_div(32*512, 256), 256, 0, stream>>>(
        xyz, nx1, gi1, 32, 1024, 512, 32, (float)(0.2*0.2));
    // 2 centroids/block, 64 rows, 1 row/lane
    sa_mlp_kernel<32, 2, 1, 3, 64, 64, 128><<<32*512/2, 256, 0, stream>>>(
        xyz, points, nx1, gi1, w1a, b1a, w1b, b1b, w1c, b1c, f1, 1024, 512);

    // ---- SA2: N=512 -> M=128, r=0.4, K=64, MLP 131->128->128->256
    fps_kernel<512><<<32, 64, 0, stream>>>(nx1, 128, fps2, nx2);
    ballquery_kernel<<<ceil_div(32*128, 256), 256, 0, stream>>>(
        nx1, nx2, gi2, 32, 512, 128, 64, (float)(0.4*0.4));
    // 1 centroid/block, 64 rows, 1 row/lane
    sa_mlp_kernel<64, 1, 1, 128, 128, 128, 256><<<32*128, 256, 0, stream>>>(
        nx1, f1, nx2, gi2, w2a, b2a, w2b, b2b, w2c, b2c, f2, 512, 128);

    // ---- SA3 (group_all): concat [4096, 259] -> MLP 259->256->512->1024 -> max over 128
    concat_kernel<<<ceil_div(4096*259, 256), 256, 0, stream>>>(nx2, f2, g3, 4096, 256);
    {
        dim3 g(ceil_div(256, 64), ceil_div(4096, 64));
        gemm_kernel<1,1><<<g, 256, 0, stream>>>(g3, w3a, b3a, h3a, 4096, 256, 259);
    }
    {
        dim3 g(ceil_div(512, 128), ceil_div(4096, 128));
        gemm128_kernel<1,1><<<g, 256, 0, stream>>>(h3a, w3b, b3b, h3b, 4096, 512, 256);
    }
    {
        dim3 g(ceil_div(1024, 128), ceil_div(4096, 128));
        gemm128_kernel<1,1><<<g, 256, 0, stream>>>(h3b, w3c, b3c, h3c, 4096, 1024, 512);
    }
    rowmax_kernel<<<ceil_div(32*1024, 256), 256, 0, stream>>>(h3c, f3, 32, 128, 1024);

    // ---- FC head
    {
        dim3 g(ceil_div(512, 64), 1);
        gemm_kernel<1,0><<<g, 256, 0, stream>>>(f3, lin1, nullptr, fc1, 32, 512, 1024);
    }
    {
        dim3 g(ceil_div(256, 64), 1);
        gemm_kernel<1,0><<<g, 256, 0, stream>>>(fc1, lin2, nullptr, fc2, 32, 256, 512);
    }
    {
        dim3 g(1, 1);
        gemm_kernel<0,1><<<g, 256, 0, stream>>>(fc2, clsw, clsb, (float*)d_out, 32, 40, 256);
    }
}